// Round 1
// baseline (551.594 us; speedup 1.0000x reference)
//
#include <hip/hip_runtime.h>
#include <hip/hip_bf16.h>
#include <cstdint>

#define D_MODEL 384
#define NHEAD 6
#define DHEAD 64
#define NPTS 2048
#define BATCH 8

typedef __attribute__((ext_vector_type(8))) short short8;
typedef __attribute__((ext_vector_type(4))) float floatx4;

__device__ __forceinline__ float bf2f(unsigned short u) {
    return __uint_as_float(((unsigned int)u) << 16);
}

// round-to-nearest-even f32 -> bf16 (finite inputs only)
__device__ __forceinline__ unsigned short f2bf(float f) {
    unsigned int u = __float_as_uint(f);
    unsigned int r = (u + 0x7FFFu + ((u >> 16) & 1u)) >> 16;
    return (unsigned short)r;
}

__device__ __forceinline__ float gelu_tanh(float x) {
    float x3 = x * x * x;
    return 0.5f * x * (1.0f + tanhf(0.7978845608028654f * (x + 0.044715f * x3)));
}

// async 16B global -> LDS (wave-uniform LDS base + lane*16)
__device__ __forceinline__ void gload_lds16(const unsigned short* g, unsigned short* l) {
    __builtin_amdgcn_global_load_lds(
        (const __attribute__((address_space(1))) unsigned int*)g,
        (__attribute__((address_space(3))) unsigned int*)l, 16, 0, 0);
}

// Weight prep: fp32 [K,N] -> bf16 [N,K] (transposed), all 8 weights in one dispatch.
__global__ __launch_bounds__(256) void k_wprep(
    const float* __restrict__ wqkv, const float* __restrict__ wao,
    const float* __restrict__ wq, const float* __restrict__ wk,
    const float* __restrict__ wv, const float* __restrict__ wm,
    const float* __restrict__ w1, const float* __restrict__ w2,
    unsigned short* __restrict__ qkvT, unsigned short* __restrict__ aoT,
    unsigned short* __restrict__ gaT, unsigned short* __restrict__ mT,
    unsigned short* __restrict__ f1T, unsigned short* __restrict__ f2T) {
    __shared__ float tile[32][33];
    int id = blockIdx.x;
    const float* src;
    unsigned short* dst;
    int K, N;
    if (id < 432)       {            src = wqkv; dst = qkvT;            K = 384; N = 1152; }
    else if (id < 576)  { id -= 432; src = wao;  dst = aoT;             K = 384; N = 384; }
    else if (id < 720)  { id -= 576; src = wq;   dst = gaT;             K = 384; N = 384; }
    else if (id < 864)  { id -= 720; src = wk;   dst = gaT + 384 * 384; K = 384; N = 384; }
    else if (id < 1008) { id -= 864; src = wv;   dst = gaT + 768 * 384; K = 384; N = 384; }
    else if (id < 1296) { id -= 1008; src = wm;  dst = mT;              K = 768; N = 384; }
    else if (id < 1584) { id -= 1296; src = w1;  dst = f1T;             K = 384; N = 768; }
    else                { id -= 1584; src = w2;  dst = f2T;             K = 768; N = 384; }
    int ntiles = N >> 5;
    int nt = id % ntiles, kt = id / ntiles;
    int tx = threadIdx.x, ty = threadIdx.y;
#pragma unroll
    for (int i = 0; i < 32; i += 8)
        tile[ty + i][tx] = src[(size_t)(kt * 32 + ty + i) * N + nt * 32 + tx];
    __syncthreads();
#pragma unroll
    for (int i = 0; i < 32; i += 8)
        dst[(size_t)(nt * 32 + ty + i) * K + kt * 32 + tx] = f2bf(tile[tx][ty + i]);
}

// features fp32 [B, D, N] -> F bf16 [B, N, D]
__global__ __launch_bounds__(256) void k_transpose_in(const float* __restrict__ feat,
                                                      unsigned short* __restrict__ f) {
    __shared__ float tile[32][33];
    int b = blockIdx.z;
    int n0 = blockIdx.x * 32, d0 = blockIdx.y * 32;
    int tx = threadIdx.x, ty = threadIdx.y;
#pragma unroll
    for (int i = 0; i < 32; i += 8)
        tile[ty + i][tx] = feat[((size_t)b * D_MODEL + d0 + ty + i) * NPTS + n0 + tx];
    __syncthreads();
#pragma unroll
    for (int i = 0; i < 32; i += 8)
        f[((size_t)b * NPTS + n0 + ty + i) * D_MODEL + d0 + tx] = f2bf(tile[tx][ty + i]);
}

// FFIN bf16 [B, N, D] -> out fp32 [B, D, N]
__global__ __launch_bounds__(256) void k_transpose_out(const unsigned short* __restrict__ f,
                                                       float* __restrict__ out) {
    __shared__ float tile[32][33];
    int b = blockIdx.z;
    int d0 = blockIdx.x * 32, n0 = blockIdx.y * 32;
    int tx = threadIdx.x, ty = threadIdx.y;
#pragma unroll
    for (int i = 0; i < 32; i += 8)
        tile[ty + i][tx] = bf2f(f[((size_t)b * NPTS + n0 + ty + i) * D_MODEL + d0 + tx]);
    __syncthreads();
#pragma unroll
    for (int i = 0; i < 32; i += 8)
        out[((size_t)b * D_MODEL + d0 + ty + i) * NPTS + n0 + tx] = tile[tx][ty + i];
}

// V slice of QKV [M,1152] (cols 768..1152) -> VT [B,H,64,NPTS]
__global__ __launch_bounds__(256) void k_vt(const unsigned short* __restrict__ qkv,
                                            unsigned short* __restrict__ vt) {
    __shared__ unsigned short tile[32][33];
    int b = blockIdx.z;
    int h = blockIdx.y >> 1, d0 = (blockIdx.y & 1) * 32;
    int n0 = blockIdx.x * 32;
    int tx = threadIdx.x, ty = threadIdx.y;
#pragma unroll
    for (int i = 0; i < 32; i += 8)
        tile[ty + i][tx] =
            qkv[((size_t)b * NPTS + n0 + ty + i) * 1152 + 768 + h * 64 + d0 + tx];
    __syncthreads();
#pragma unroll
    for (int i = 0; i < 32; i += 8)
        vt[(((size_t)(b * NHEAD + h) * 64) + d0 + ty + i) * NPTS + n0 + tx] = tile[tx][ty + i];
}

// LayerNorm over D=384 (bf16 in/out, fp32 g/b), one block (128 thr) per row
__global__ __launch_bounds__(128) void k_layernorm(const unsigned short* __restrict__ x,
                                                   const float* __restrict__ g,
                                                   const float* __restrict__ bt,
                                                   unsigned short* __restrict__ y) {
    int row = blockIdx.x, t = threadIdx.x;
    const unsigned short* xr = x + (size_t)row * D_MODEL;
    float v0 = bf2f(xr[t]), v1 = bf2f(xr[t + 128]), v2 = bf2f(xr[t + 256]);
    float s = v0 + v1 + v2;
    float s2 = v0 * v0 + v1 * v1 + v2 * v2;
#pragma unroll
    for (int off = 32; off > 0; off >>= 1) {
        s += __shfl_xor(s, off, 64);
        s2 += __shfl_xor(s2, off, 64);
    }
    __shared__ float ps[2], ps2[2];
    if ((t & 63) == 0) { ps[t >> 6] = s; ps2[t >> 6] = s2; }
    __syncthreads();
    s = ps[0] + ps[1];
    s2 = ps2[0] + ps2[1];
    float mean = s * (1.0f / 384.0f);
    float var = s2 * (1.0f / 384.0f) - mean * mean;
    var = fmaxf(var, 0.0f);
    float inv = 1.0f / sqrtf(var + 1e-5f);
    unsigned short* yr = y + (size_t)row * D_MODEL;
    yr[t]       = f2bf((v0 - mean) * inv * g[t]       + bt[t]);
    yr[t + 128] = f2bf((v1 - mean) * inv * g[t + 128] + bt[t + 128]);
    yr[t + 256] = f2bf((v2 - mean) * inv * g[t + 256] + bt[t + 256]);
}

// KNN: LDS-resident candidates, 8 threads/query, interleaved partitions.
__global__ __launch_bounds__(256) void k_knn(const float* __restrict__ coords,
                                             int* __restrict__ idx) {
    __shared__ float4 cpts[NPTS];
    __shared__ unsigned long long mbuf[32][8][8];
    int b = blockIdx.x >> 6;
    int n0 = (blockIdx.x & 63) * 32;
    const float* cb = coords + (size_t)b * 3 * NPTS;
    int tid = threadIdx.x;
#pragma unroll
    for (int i = 0; i < 8; i++) {
        int m = tid + i * 256;
        float x = cb[m], y = cb[NPTS + m], z = cb[2 * NPTS + m];
        float sq = __fadd_rn(__fadd_rn(__fmul_rn(x, x), __fmul_rn(y, y)), __fmul_rn(z, z));
        cpts[m] = make_float4(x, y, z, sq);
    }
    __syncthreads();
    int q = tid >> 3;
    int part = tid & 7;
    int n = n0 + q;
    float4 qp = cpts[n];
    float qx = qp.x, qy = qp.y, qz = qp.z, sqn = qp.w;
    unsigned long long heap[8];
#pragma unroll
    for (int k = 0; k < 8; k++) heap[k] = 0xFFFFFFFFFFFFFFFFull;
    for (int j = 0; j < 256; j++) {
        int m = j * 8 + part;
        float4 cp = cpts[m];
        float dot = __fadd_rn(__fadd_rn(__fmul_rn(qx, cp.x), __fmul_rn(qy, cp.y)),
                              __fmul_rn(qz, cp.z));
        float d2 = __fsub_rn(__fadd_rn(sqn, cp.w), __fmul_rn(2.0f, dot));
        unsigned int u = __float_as_uint(d2);
        u = (u & 0x80000000u) ? ~u : (u | 0x80000000u);
        unsigned long long key = ((unsigned long long)u << 32) | (unsigned int)m;
        if (key < heap[7]) {
            heap[7] = key;
#pragma unroll
            for (int t2 = 7; t2 > 0; t2--) {
                if (heap[t2] < heap[t2 - 1]) {
                    unsigned long long tmp = heap[t2];
                    heap[t2] = heap[t2 - 1];
                    heap[t2 - 1] = tmp;
                }
            }
        }
    }
#pragma unroll
    for (int k = 0; k < 8; k++) mbuf[q][part][k] = heap[k];
    __syncthreads();
    if (part == 0) {
        int p[8] = {0, 0, 0, 0, 0, 0, 0, 0};
        int* outr = idx + ((size_t)b * NPTS + n) * 8;
#pragma unroll
        for (int k = 0; k < 8; k++) {
            unsigned long long best = mbuf[q][0][p[0]];
            int bi = 0;
#pragma unroll
            for (int c = 1; c < 8; c++) {
                unsigned long long v = mbuf[q][c][p[c]];
                if (v < best) { best = v; bi = c; }
            }
            p[bi]++;
            outr[k] = (int)(best & 0xFFFFFFFFu);
        }
    }
}

// MFMA GEMM v5: 128x128 tile, BK=64. BOTH operands staged to LDS via async
// global_load_lds (16B, zero staging VALU), layout = two 128x32 chunks per
// operand (pitch 64B, proven v3 bank pattern). Operand-swapped MFMA
// (acc = W_frag x A_frag = C^T layout) so the epilogue's 4 acc regs per lane
// are contiguous columns -> ushort4 stores, uint2 res loads, float4 bias.
// A bf16 [M,K] (lda), WT bf16 [N,K], bias fp32, res/C bf16 (ldc).
__global__ __launch_bounds__(256) void k_gemm(const unsigned short* __restrict__ A, int lda,
                                              const unsigned short* __restrict__ WT,
                                              const float* __restrict__ bias,
                                              const unsigned short* __restrict__ res,
                                              unsigned short* __restrict__ C, int ldc,
                                              int K, int act) {
    __shared__ unsigned short Alds[2 * 128 * 32];  // 16 KB: [kc][row][32]
    __shared__ unsigned short Wlds[2 * 128 * 32];  // 16 KB: [kc][nrow][32]
    int tid = threadIdx.x;
    int wv = tid >> 6, lane = tid & 63;
    int l15 = lane & 15, quad = lane >> 4;
    int row0 = blockIdx.y * 128, col0 = blockIdx.x * 128;
    int wm = wv >> 1, wn = wv & 1;
    int wbase = tid & 192;  // wv*64
    floatx4 acc[4][4];
#pragma unroll
    for (int i = 0; i < 4; i++)
#pragma unroll
        for (int j = 0; j < 4; j++) acc[i][j] = (floatx4){0.f, 0.f, 0.f, 0.f};
    for (int k0 = 0; k0 < K; k0 += 64) {
#pragma unroll
        for (int i = 0; i < 4; i++) {
            int idx = i * 256 + tid;
            int kc = idx >> 9, row = (idx >> 2) & 127, ko = idx & 3;
            unsigned short* ldst = Alds + (size_t)(i * 256 + wbase) * 8;  // idx*16B, wave-uniform
            gload_lds16(A + (size_t)(row0 + row) * lda + k0 + kc * 32 + ko * 8, ldst);
            unsigned short* ldstw = Wlds + (size_t)(i * 256 + wbase) * 8;
            gload_lds16(WT + (size_t)(col0 + row) * K + k0 + kc * 32 + ko * 8, ldstw);
        }
        __syncthreads();  // drains global_load_lds
#pragma unroll
        for (int kc = 0; kc < 2; kc++) {
            short8 af[4], bf[4];
#pragma unroll
            for (int i = 0; i < 4; i++)
                af[i] = *(const short8*)&Alds[kc * 4096 + (wm * 64 + i * 16 + l15) * 32 + quad * 8];
#pragma unroll
            for (int j = 0; j < 4; j++)
                bf[j] = *(const short8*)&Wlds[kc * 4096 + (wn * 64 + j * 16 + l15) * 32 + quad * 8];
#pragma unroll
            for (int i = 0; i < 4; i++)
#pragma unroll
                for (int j = 0; j < 4; j++)
                    acc[i][j] =
                        __builtin_amdgcn_mfma_f32_16x16x32_bf16(bf[j], af[i], acc[i][j], 0, 0, 0);
        }
        __syncthreads();
    }
    // acc[i][j] is C^T-layout: D rows = n (quad*4+reg within j-tile), cols = m (l15)
#pragma unroll
    for (int i = 0; i < 4; i++) {
        int r = row0 + wm * 64 + i * 16 + l15;
#pragma unroll
        for (int j = 0; j < 4; j++) {
            int cb = col0 + wn * 64 + j * 16 + quad * 4;
            float4 bv = bias ? *(const float4*)(bias + cb) : make_float4(0.f, 0.f, 0.f, 0.f);
            float v0 = acc[i][j][0] + bv.x;
            float v1 = acc[i][j][1] + bv.y;
            float v2 = acc[i][j][2] + bv.z;
            float v3 = acc[i][j][3] + bv.w;
            if (act == 1) {
                v0 = gelu_tanh(v0); v1 = gelu_tanh(v1);
                v2 = gelu_tanh(v2); v3 = gelu_tanh(v3);
            }
            if (res) {
                uint2 rv = *(const uint2*)(res + (size_t)r * ldc + cb);
                const unsigned short* rs = (const unsigned short*)&rv;
                v0 += bf2f(rs[0]); v1 += bf2f(rs[1]);
                v2 += bf2f(rs[2]); v3 += bf2f(rs[3]);
            }
            ushort4 u;
            u.x = f2bf(v0); u.y = f2bf(v1); u.z = f2bf(v2); u.w = f2bf(v3);
            *(ushort4*)(C + (size_t)r * ldc + cb) = u;
        }
    }
}

// MFMA flash attention v4: no-max softmax (p = exp2(s), Q pre-scaled by
// 0.125*log2e at load), V pre-transposed in global (VT [B,H,64,NPTS]).
__global__ __launch_bounds__(256) void k_attn(const unsigned short* __restrict__ qkv,
                                              const unsigned short* __restrict__ vt,
                                              unsigned short* __restrict__ attn) {
    __shared__ unsigned short Klds[64 * 72];       // [key][dim]
    __shared__ unsigned short VT[64 * 72];         // [dim][key]
    __shared__ unsigned short Plds[4][2][16 * 40]; // per-wave [query][key] pitch 40
    __shared__ float lSm[4][32];
    int b = blockIdx.z, h = blockIdx.y;
    int tid = threadIdx.x;
    int wv = tid >> 6, lane = tid & 63;
    int l15 = lane & 15, quad = lane >> 4;
    int qbase = blockIdx.x * 128 + wv * 32;
    const unsigned short* qkvb = qkv + (size_t)b * NPTS * 1152;
    const unsigned short* vtb = vt + (size_t)(b * NHEAD + h) * 64 * NPTS;
    const float SC = 0.18033688011112042f;  // 0.125 * log2(e)
    short8 qf[2][2];
#pragma unroll
    for (int qt = 0; qt < 2; qt++) {
        const unsigned short* qptr =
            qkvb + (size_t)(qbase + qt * 16 + l15) * 1152 + h * 64 + quad * 8;
        qf[qt][0] = *(const short8*)qptr;
        qf[qt][1] = *(const short8*)(qptr + 32);
#pragma unroll
        for (int g = 0; g < 2; g++) {  // fold softmax scale into Q once
            short8 v = qf[qt][g];
#pragma unroll
            for (int e = 0; e < 8; e++)
                v[e] = (short)f2bf(bf2f((unsigned short)v[e]) * SC);
            qf[qt][g] = v;
        }
    }
    floatx4 o[2][4];
#pragma unroll
    for (int qt = 0; qt < 2; qt++)
#pragma unroll
        for (int ct = 0; ct < 4; ct++) o[qt][ct] = (floatx4){0.f, 0.f, 0.f, 0.f};
    float lacc[2][4];
#pragma unroll
    for (int qt = 0; qt < 2; qt++)
#pragma unroll
        for (int r = 0; r < 4; r++) lacc[qt][r] = 0.0f;
    for (int k0 = 0; k0 < NPTS; k0 += 64) {
#pragma unroll
        for (int i = 0; i < 2; i++) {
            int s = tid + i * 256;
            int key = s >> 3, dg = s & 7;
            *(uint4*)&Klds[key * 72 + dg * 8] =
                *(const uint4*)(qkvb + (size_t)(k0 + key) * 1152 + 384 + h * 64 + dg * 8);
            int dim = s >> 3, kc = s & 7;
            *(uint4*)&VT[dim * 72 + kc * 8] =
                *(const uint4*)(vtb + (size_t)dim * NPTS + k0 + kc * 8);
        }
        __syncthreads();
#pragma unroll
        for (int qt = 0; qt < 2; qt++) {
            floatx4 s4[4];
#pragma unroll
            for (int ct = 0; ct < 4; ct++) {
                short8 kf0 = *(const short8*)&Klds[(ct * 16 + l15) * 72 + quad * 8];
                short8 kf1 = *(const short8*)&Klds[(ct * 16 + l15) * 72 + 32 + quad * 8];
                floatx4 z = (floatx4){0.f, 0.f, 0.f, 0.f};
                z = __builtin_amdgcn_mfma_f32_16x16x32_bf16(qf[qt][0], kf0, z, 0, 0, 0);
                z = __builtin_amdgcn_mfma_f32_16x16x32_bf16(qf[qt][1], kf1, z, 0, 0, 0);
                s4[ct] = z;
            }
            unsigned short* pw = &Plds[wv][qt][0];
#pragma unroll
            for (int ct = 0; ct < 4; ct++)
#pragma unroll
                for (int r = 0; r < 4; r++) {
                    float p = exp2f(s4[ct][r]);
                    lacc[qt][r] += p;
                    pw[(quad * 4 + r) * 40 + ct * 16 + l15] = f2bf(p);
                }
        }
        short8 pf[2][2];
#pragma unroll
        for (int qt = 0; qt < 2; qt++)
#pragma unroll
            for (int g = 0; g < 2; g++)
                pf[qt][g] = *(const short8*)&Plds[wv][qt][l15 * 40 + g * 32 + quad * 8];
#pragma unroll
        for (int ct = 0; ct < 4; ct++) {
            short8 vt0 = *(const short8*)&VT[(ct * 16 + l15) * 72 + quad * 8];
            short8 vt1 = *(const short8*)&VT[(ct * 16 + l15) * 72 + 32 + quad * 8];
#pragma unroll
            for (int qt = 0; qt < 2; qt++) {
                o[qt][ct] = __builtin_amdgcn_mfma_f32_16x16x32_bf16(vt0, pf[qt][0], o[qt][ct], 0, 0, 0);
                o[qt][ct] = __builtin_amdgcn_mfma_f32_16x16x32_bf16(vt1, pf[qt][1], o[qt][ct], 0, 0, 0);
            }
        }
        __syncthreads();
    }
#pragma unroll
    for (int off = 1; off < 16; off <<= 1)
#pragma unroll
        for (int qt = 0; qt < 2; qt++)
#pragma unroll
            for (int r = 0; r < 4; r++) lacc[qt][r] += __shfl_xor(lacc[qt][r], off, 64);
    if (l15 == 0) {
#pragma unroll
        for (int qt = 0; qt < 2; qt++)
#pragma unroll
            for (int r = 0; r < 4; r++) lSm[wv][qt * 16 + quad * 4 + r] = lacc[qt][r];
    }
    __syncthreads();
#pragma unroll
    for (int qt = 0; qt < 2; qt++) {
        float linv = 1.0f / lSm[wv][qt * 16 + l15];
#pragma unroll
        for (int ct = 0; ct < 4; ct++) {
            ushort4 u;
            u.x = f2bf(o[qt][ct][0] * linv);
            u.y = f2bf(o[qt][ct][1] * linv);
            u.z = f2bf(o[qt][ct][2] * linv);
            u.w = f2bf(o[qt][ct][3] * linv);
            *(ushort4*)(attn + ((size_t)b * NPTS + qbase + qt * 16 + l15) * 384 + h * 64 +
                        ct * 16 + quad * 4) = u;
        }
    }
}

// Graph attention: gq/nk/nv are column-slices of GAP [M,1152]. One wave per point.
// Writes geom into CAT[:, 384:768] (row stride 768).
__global__ __launch_bounds__(64) void k_geom(const unsigned short* __restrict__ gap,
                                             const int* __restrict__ idx,
                                             unsigned short* __restrict__ cat) {
    int r = blockIdx.x;
    int b = r >> 11;
    int t = threadIdx.x;
    int nb[8];
#pragma unroll
    for (int k = 0; k < 8; k++) nb[k] = idx[(size_t)r * 8 + k];
    const unsigned short* gqr = gap + (size_t)r * 1152;
    float qv[6];
#pragma unroll
    for (int j = 0; j < 6; j++) qv[j] = bf2f(gqr[t + 64 * j]);
    float s[8];
#pragma unroll
    for (int k = 0; k < 8; k++) {
        const unsigned short* nkr = gap + ((size_t)b * NPTS + nb[k]) * 1152 + 384;
        float acc = 0.0f;
#pragma unroll
        for (int j = 0; j < 6; j++) acc += qv[j] * bf2f(nkr[t + 64 * j]);
#pragma unroll
        for (int mm = 32; mm > 0; mm >>= 1) acc += __shfl_xor(acc, mm, 64);
        s[k] = acc * 0.05103103630798287f;  // 1/sqrt(384)
    }
    float mx = s[0];
#pragma unroll
    for (int k = 1; k < 8; k++) mx = fmaxf(mx, s[k]);
    float w[8];
    float sum = 0.0f;
#pragma unroll
    for (int k = 0; k < 8; k++) { w[k] = __expf(s[k] - mx); sum += w[k]; }
    float inv = 1.0f / sum;
    unsigned short* outr = cat + (size_t)r * 768 + 384;
#pragma unroll
    for (int j = 0; j < 6; j++) {
        int d = t + 64 * j;
        float acc = 0.0f;
#pragma unroll
        for (int k = 0; k < 8; k++)
            acc += w[k] * bf2f(gap[((size_t)b * NPTS + nb[k]) * 1152 + 768 + d]);
        outr[d] = f2bf(acc * inv);
    }
}

extern "C" void kernel_launch(void* const* d_in, const int* in_sizes, int n_in,
                              void* d_out, int out_size, void* d_ws, size_t ws_size,
                              hipStream_t stream) {
    (void)in_sizes; (void)n_in; (void)out_size; (void)ws_size;
    const float* coords     = (const float*)d_in[0];
    const float* features   = (const float*)d_in[1];
    const float* ln1_g      = (const float*)d_in[2];
    const float* ln1_b      = (const float*)d_in[3];
    const float* w_qkv      = (const float*)d_in[4];
    const float* w_attn_out = (const float*)d_in[5];
    const float* b_attn_out = (const float*)d_in[6];
    const float* ga_wq      = (const float*)d_in[7];
    const float* ga_wk      = (const float*)d_in[8];
    const float* ga_wv      = (const float*)d_in[9];
    const float* merge_w    = (const float*)d_in[10];
    const float* merge_b    = (const float*)d_in[11];
    const float* ln2_g      = (const float*)d_in[12];
    const float* ln2_b      = (const float*)d_in[13];
    const float* ff_w1      = (const float*)d_in[14];
    const float* ff_b1      = (const float*)d_in[15];
    const float* ff_w2      = (const float*)d_in[16];
    const float* ff_b2      = (const float*)d_in[17];

    // Workspace (bf16 units of SZ = 6,291,456 elems = 12 MiB). Overlay schedule:
    //   u0 F | u1 NF->HB | u2-4 QKV -> (CAT=u2-3, GAP=u4-6 after attn/AO) |
    //   u5 ATTN | u6 VT (dead before GAP gemm) | F2=u4 after geom | T1=u5-6 |
    //   FFIN=u2 | IDX + transposed weights after u7 (~4.3 MB). Peak ~100 MiB.
    unsigned short* W0 = (unsigned short*)d_ws;
    const size_t SZ = (size_t)BATCH * NPTS * D_MODEL;  // 6291456
    unsigned short* F    = W0 + 0 * SZ;
    unsigned short* NF   = W0 + 1 * SZ;
    unsigned short* QKV  = W0 + 2 * SZ;   // 3 units
    unsigned short* ATTN = W0 + 5 * SZ;
    unsigned short* VT   = W0 + 6 * SZ;   // [B,H,64,NPTS] = 1 unit
    unsigned short* CAT  = W0 + 2 * SZ;   // 2 units [M,768]
    unsigned short* GAP  = W0 + 4 * SZ;   // 3 units [M,1152]
    unsigned short* F2   = W0 + 4 * SZ;   // after GAP dead
    unsigned short* HB   = W0 + 1 * SZ;
    unsigned short* T1   = W0 + 5 * SZ;   // 2 units [M,768]
    unsigned short* FFIN = W0 + 2 * SZ;
    int*            IDX  = (int*)(W0 + 7 * SZ);
    unsigned short* WTS  = W0 + 7 * SZ + 262144;  // after IDX (512 KB)
    unsigned short* qkvT = WTS;                     // [1152,384]
    unsigned short* aoT  = qkvT + 442368;           // [384,384]
    unsigned short* gaT  = aoT + 147456;            // [1152,384]
    unsigned short* mT   = gaT + 442368;            // [384,768]
    unsigned short* f1T  = mT + 294912;             // [768,384]
    unsigned short* f2T  = f1T + 294912;            // [384,768]

    const int M = BATCH * NPTS;  // 16384

    k_wprep<<<1872, dim3(32, 8), 0, stream>>>(w_qkv, w_attn_out, ga_wq, ga_wk, ga_wv,
                                              merge_w, ff_w1, ff_w2,
                                              qkvT, aoT, gaT, mT, f1T, f2T);
    k_transpose_in<<<dim3(NPTS / 32, D_MODEL / 32, BATCH), dim3(32, 8), 0, stream>>>(features, F);
    k_layernorm<<<M, 128, 0, stream>>>(F, ln1_g, ln1_b, NF);
    k_knn<<<BATCH * (NPTS / 32), 256, 0, stream>>>(coords, IDX);
    // QKV = NF @ w_qkv
    k_gemm<<<dim3(9, M / 128), 256, 0, stream>>>(NF, 384, qkvT, nullptr, nullptr,
                                                 QKV, 1152, 384, 0);
    k_vt<<<dim3(NPTS / 32, 2 * NHEAD, BATCH), dim3(32, 8), 0, stream>>>(QKV, VT);
    k_attn<<<dim3(NPTS / 128, NHEAD, BATCH), 256, 0, stream>>>(QKV, VT, ATTN);
    // CAT[:, :384] = ATTN @ w_attn_out + b_attn_out
    k_gemm<<<dim3(3, M / 128), 256, 0, stream>>>(ATTN, 384, aoT, b_attn_out, nullptr,
                                                 CAT, 768, 384, 0);
    // GAP = NF @ [ga_wq | ga_wk | ga_wv]
    k_gemm<<<dim3(9, M / 128), 256, 0, stream>>>(NF, 384, gaT, nullptr, nullptr,
                                                 GAP, 1152, 384, 0);
    k_geom<<<M, 64, 0, stream>>>(GAP, IDX, CAT);
    // F2 = CAT @ merge_w + merge_b + F
    k_gemm<<<dim3(3, M / 128), 256, 0, stream>>>(CAT, 768, mT, merge_b, F,
                                                 F2, 384, 768, 0);
    k_layernorm<<<M, 128, 0, stream>>>(F2, ln2_g, ln2_b, HB);
    // T1 = gelu(HB @ ff_w1 + ff_b1)
    k_gemm<<<dim3(6, M / 128), 256, 0, stream>>>(HB, 384, f1T, ff_b1, nullptr,
                                                 T1, 768, 384, 1);
    // FFIN = F2 + T1 @ ff_w2 + ff_b2
    k_gemm<<<dim3(3, M / 128), 256, 0, stream>>>(T1, 768, f2T, ff_b2, F2,
                                                 FFIN, 384, 768, 0);
    k_transpose_out<<<dim3(D_MODEL / 32, NPTS / 32, BATCH), dim3(32, 8), 0, stream>>>(
        FFIN, (float*)d_out);
}

// Round 3
// 506.802 us; speedup vs baseline: 1.0884x; 1.0884x over previous
//
#include <hip/hip_runtime.h>
#include <hip/hip_bf16.h>
#include <cstdint>

#define D_MODEL 384
#define NHEAD 6
#define DHEAD 64
#define NPTS 2048
#define BATCH 8

typedef __attribute__((ext_vector_type(8))) short short8;
typedef __attribute__((ext_vector_type(4))) float floatx4;
typedef __attribute__((ext_vector_type(2))) unsigned int u32x2;
typedef __attribute__((ext_vector_type(4))) unsigned int u32x4;

__device__ __forceinline__ float bf2f(unsigned short u) {
    return __uint_as_float(((unsigned int)u) << 16);
}

// round-to-nearest-even f32 -> bf16 (finite inputs only)
__device__ __forceinline__ unsigned short f2bf(float f) {
    unsigned int u = __float_as_uint(f);
    unsigned int r = (u + 0x7FFFu + ((u >> 16) & 1u)) >> 16;
    return (unsigned short)r;
}

// v_cvt_pk_bf16_f32: pack two f32 -> {bf16(lo), bf16(hi)} in one u32 (RNE)
__device__ __forceinline__ unsigned cvtpk(float lo, float hi) {
    unsigned r;
    asm("v_cvt_pk_bf16_f32 %0, %1, %2" : "=v"(r) : "v"(lo), "v"(hi));
    return r;
}

// ds_read_b64_tr_b16: per-lane gather of 4 bf16 at addr + j*16 elems (j=0..3)
#define TR16(dst, addr, imm) \
    asm volatile("ds_read_b64_tr_b16 %0, %1 offset:" #imm : "=v"(dst) : "v"(addr))

__device__ __forceinline__ float gelu_tanh(float x) {
    float x3 = x * x * x;
    return 0.5f * x * (1.0f + tanhf(0.7978845608028654f * (x + 0.044715f * x3)));
}

// async 16B global -> LDS (wave-uniform LDS base + lane*16)
__device__ __forceinline__ void gload_lds16(const unsigned short* g, unsigned short* l) {
    __builtin_amdgcn_global_load_lds(
        (const __attribute__((address_space(1))) unsigned int*)g,
        (__attribute__((address_space(3))) unsigned int*)l, 16, 0, 0);
}

// Weight prep: fp32 [K,N] -> bf16 [N,K] (transposed), all 8 weights in one dispatch.
__global__ __launch_bounds__(256) void k_wprep(
    const float* __restrict__ wqkv, const float* __restrict__ wao,
    const float* __restrict__ wq, const float* __restrict__ wk,
    const float* __restrict__ wv, const float* __restrict__ wm,
    const float* __restrict__ w1, const float* __restrict__ w2,
    unsigned short* __restrict__ qkvT, unsigned short* __restrict__ aoT,
    unsigned short* __restrict__ gaT, unsigned short* __restrict__ mT,
    unsigned short* __restrict__ f1T, unsigned short* __restrict__ f2T) {
    __shared__ float tile[32][33];
    int id = blockIdx.x;
    const float* src;
    unsigned short* dst;
    int K, N;
    if (id < 432)       {            src = wqkv; dst = qkvT;            K = 384; N = 1152; }
    else if (id < 576)  { id -= 432; src = wao;  dst = aoT;             K = 384; N = 384; }
    else if (id < 720)  { id -= 576; src = wq;   dst = gaT;             K = 384; N = 384; }
    else if (id < 864)  { id -= 720; src = wk;   dst = gaT + 384 * 384; K = 384; N = 384; }
    else if (id < 1008) { id -= 864; src = wv;   dst = gaT + 768 * 384; K = 384; N = 384; }
    else if (id < 1296) { id -= 1008; src = wm;  dst = mT;              K = 768; N = 384; }
    else if (id < 1584) { id -= 1296; src = w1;  dst = f1T;             K = 384; N = 768; }
    else                { id -= 1584; src = w2;  dst = f2T;             K = 768; N = 384; }
    int ntiles = N >> 5;
    int nt = id % ntiles, kt = id / ntiles;
    int tx = threadIdx.x, ty = threadIdx.y;
#pragma unroll
    for (int i = 0; i < 32; i += 8)
        tile[ty + i][tx] = src[(size_t)(kt * 32 + ty + i) * N + nt * 32 + tx];
    __syncthreads();
#pragma unroll
    for (int i = 0; i < 32; i += 8)
        dst[(size_t)(nt * 32 + ty + i) * K + kt * 32 + tx] = f2bf(tile[tx][ty + i]);
}

// features fp32 [B, D, N] -> F bf16 [B, N, D]
__global__ __launch_bounds__(256) void k_transpose_in(const float* __restrict__ feat,
                                                      unsigned short* __restrict__ f) {
    __shared__ float tile[32][33];
    int b = blockIdx.z;
    int n0 = blockIdx.x * 32, d0 = blockIdx.y * 32;
    int tx = threadIdx.x, ty = threadIdx.y;
#pragma unroll
    for (int i = 0; i < 32; i += 8)
        tile[ty + i][tx] = feat[((size_t)b * D_MODEL + d0 + ty + i) * NPTS + n0 + tx];
    __syncthreads();
#pragma unroll
    for (int i = 0; i < 32; i += 8)
        f[((size_t)b * NPTS + n0 + ty + i) * D_MODEL + d0 + tx] = f2bf(tile[tx][ty + i]);
}

// FFIN bf16 [B, N, D] -> out fp32 [B, D, N]
__global__ __launch_bounds__(256) void k_transpose_out(const unsigned short* __restrict__ f,
                                                       float* __restrict__ out) {
    __shared__ float tile[32][33];
    int b = blockIdx.z;
    int d0 = blockIdx.x * 32, n0 = blockIdx.y * 32;
    int tx = threadIdx.x, ty = threadIdx.y;
#pragma unroll
    for (int i = 0; i < 32; i += 8)
        tile[ty + i][tx] = bf2f(f[((size_t)b * NPTS + n0 + ty + i) * D_MODEL + d0 + tx]);
    __syncthreads();
#pragma unroll
    for (int i = 0; i < 32; i += 8)
        out[((size_t)b * D_MODEL + d0 + ty + i) * NPTS + n0 + tx] = tile[tx][ty + i];
}

// V slice of QKV [M,1152] (cols 768..1152) -> VT [B,H,64,NPTS]
__global__ __launch_bounds__(256) void k_vt(const unsigned short* __restrict__ qkv,
                                            unsigned short* __restrict__ vt) {
    __shared__ unsigned short tile[32][33];
    int b = blockIdx.z;
    int h = blockIdx.y >> 1, d0 = (blockIdx.y & 1) * 32;
    int n0 = blockIdx.x * 32;
    int tx = threadIdx.x, ty = threadIdx.y;
#pragma unroll
    for (int i = 0; i < 32; i += 8)
        tile[ty + i][tx] =
            qkv[((size_t)b * NPTS + n0 + ty + i) * 1152 + 768 + h * 64 + d0 + tx];
    __syncthreads();
#pragma unroll
    for (int i = 0; i < 32; i += 8)
        vt[(((size_t)(b * NHEAD + h) * 64) + d0 + ty + i) * NPTS + n0 + tx] = tile[tx][ty + i];
}

// LayerNorm over D=384 (bf16 in/out, fp32 g/b), one block (128 thr) per row
__global__ __launch_bounds__(128) void k_layernorm(const unsigned short* __restrict__ x,
                                                   const float* __restrict__ g,
                                                   const float* __restrict__ bt,
                                                   unsigned short* __restrict__ y) {
    int row = blockIdx.x, t = threadIdx.x;
    const unsigned short* xr = x + (size_t)row * D_MODEL;
    float v0 = bf2f(xr[t]), v1 = bf2f(xr[t + 128]), v2 = bf2f(xr[t + 256]);
    float s = v0 + v1 + v2;
    float s2 = v0 * v0 + v1 * v1 + v2 * v2;
#pragma unroll
    for (int off = 32; off > 0; off >>= 1) {
        s += __shfl_xor(s, off, 64);
        s2 += __shfl_xor(s2, off, 64);
    }
    __shared__ float ps[2], ps2[2];
    if ((t & 63) == 0) { ps[t >> 6] = s; ps2[t >> 6] = s2; }
    __syncthreads();
    s = ps[0] + ps[1];
    s2 = ps2[0] + ps2[1];
    float mean = s * (1.0f / 384.0f);
    float var = s2 * (1.0f / 384.0f) - mean * mean;
    var = fmaxf(var, 0.0f);
    float inv = 1.0f / sqrtf(var + 1e-5f);
    unsigned short* yr = y + (size_t)row * D_MODEL;
    yr[t]       = f2bf((v0 - mean) * inv * g[t]       + bt[t]);
    yr[t + 128] = f2bf((v1 - mean) * inv * g[t + 128] + bt[t + 128]);
    yr[t + 256] = f2bf((v2 - mean) * inv * g[t + 256] + bt[t + 256]);
}

// KNN: LDS-resident candidates, 8 threads/query, interleaved partitions.
__global__ __launch_bounds__(256) void k_knn(const float* __restrict__ coords,
                                             int* __restrict__ idx) {
    __shared__ float4 cpts[NPTS];
    __shared__ unsigned long long mbuf[32][8][8];
    int b = blockIdx.x >> 6;
    int n0 = (blockIdx.x & 63) * 32;
    const float* cb = coords + (size_t)b * 3 * NPTS;
    int tid = threadIdx.x;
#pragma unroll
    for (int i = 0; i < 8; i++) {
        int m = tid + i * 256;
        float x = cb[m], y = cb[NPTS + m], z = cb[2 * NPTS + m];
        float sq = __fadd_rn(__fadd_rn(__fmul_rn(x, x), __fmul_rn(y, y)), __fmul_rn(z, z));
        cpts[m] = make_float4(x, y, z, sq);
    }
    __syncthreads();
    int q = tid >> 3;
    int part = tid & 7;
    int n = n0 + q;
    float4 qp = cpts[n];
    float qx = qp.x, qy = qp.y, qz = qp.z, sqn = qp.w;
    unsigned long long heap[8];
#pragma unroll
    for (int k = 0; k < 8; k++) heap[k] = 0xFFFFFFFFFFFFFFFFull;
    for (int j = 0; j < 256; j++) {
        int m = j * 8 + part;
        float4 cp = cpts[m];
        float dot = __fadd_rn(__fadd_rn(__fmul_rn(qx, cp.x), __fmul_rn(qy, cp.y)),
                              __fmul_rn(qz, cp.z));
        float d2 = __fsub_rn(__fadd_rn(sqn, cp.w), __fmul_rn(2.0f, dot));
        unsigned int u = __float_as_uint(d2);
        u = (u & 0x80000000u) ? ~u : (u | 0x80000000u);
        unsigned long long key = ((unsigned long long)u << 32) | (unsigned int)m;
        if (key < heap[7]) {
            heap[7] = key;
#pragma unroll
            for (int t2 = 7; t2 > 0; t2--) {
                if (heap[t2] < heap[t2 - 1]) {
                    unsigned long long tmp = heap[t2];
                    heap[t2] = heap[t2 - 1];
                    heap[t2 - 1] = tmp;
                }
            }
        }
    }
#pragma unroll
    for (int k = 0; k < 8; k++) mbuf[q][part][k] = heap[k];
    __syncthreads();
    if (part == 0) {
        int p[8] = {0, 0, 0, 0, 0, 0, 0, 0};
        int* outr = idx + ((size_t)b * NPTS + n) * 8;
#pragma unroll
        for (int k = 0; k < 8; k++) {
            unsigned long long best = mbuf[q][0][p[0]];
            int bi = 0;
#pragma unroll
            for (int c = 1; c < 8; c++) {
                unsigned long long v = mbuf[q][c][p[c]];
                if (v < best) { best = v; bi = c; }
            }
            p[bi]++;
            outr[k] = (int)(best & 0xFFFFFFFFu);
        }
    }
}

// MFMA GEMM v5: 128x128 tile, BK=64. BOTH operands staged to LDS via async
// global_load_lds (16B, zero staging VALU), layout = two 128x32 chunks per
// operand (pitch 64B, proven v3 bank pattern). Operand-swapped MFMA
// (acc = W_frag x A_frag = C^T layout) so the epilogue's 4 acc regs per lane
// are contiguous columns -> ushort4 stores, uint2 res loads, float4 bias.
// A bf16 [M,K] (lda), WT bf16 [N,K], bias fp32, res/C bf16 (ldc).
__global__ __launch_bounds__(256) void k_gemm(const unsigned short* __restrict__ A, int lda,
                                              const unsigned short* __restrict__ WT,
                                              const float* __restrict__ bias,
                                              const unsigned short* __restrict__ res,
                                              unsigned short* __restrict__ C, int ldc,
                                              int K, int act) {
    __shared__ unsigned short Alds[2 * 128 * 32];  // 16 KB: [kc][row][32]
    __shared__ unsigned short Wlds[2 * 128 * 32];  // 16 KB: [kc][nrow][32]
    int tid = threadIdx.x;
    int wv = tid >> 6, lane = tid & 63;
    int l15 = lane & 15, quad = lane >> 4;
    int row0 = blockIdx.y * 128, col0 = blockIdx.x * 128;
    int wm = wv >> 1, wn = wv & 1;
    int wbase = tid & 192;  // wv*64
    floatx4 acc[4][4];
#pragma unroll
    for (int i = 0; i < 4; i++)
#pragma unroll
        for (int j = 0; j < 4; j++) acc[i][j] = (floatx4){0.f, 0.f, 0.f, 0.f};
    for (int k0 = 0; k0 < K; k0 += 64) {
#pragma unroll
        for (int i = 0; i < 4; i++) {
            int idx = i * 256 + tid;
            int kc = idx >> 9, row = (idx >> 2) & 127, ko = idx & 3;
            unsigned short* ldst = Alds + (size_t)(i * 256 + wbase) * 8;  // idx*16B, wave-uniform
            gload_lds16(A + (size_t)(row0 + row) * lda + k0 + kc * 32 + ko * 8, ldst);
            unsigned short* ldstw = Wlds + (size_t)(i * 256 + wbase) * 8;
            gload_lds16(WT + (size_t)(col0 + row) * K + k0 + kc * 32 + ko * 8, ldstw);
        }
        __syncthreads();  // drains global_load_lds
#pragma unroll
        for (int kc = 0; kc < 2; kc++) {
            short8 af[4], bf[4];
#pragma unroll
            for (int i = 0; i < 4; i++)
                af[i] = *(const short8*)&Alds[kc * 4096 + (wm * 64 + i * 16 + l15) * 32 + quad * 8];
#pragma unroll
            for (int j = 0; j < 4; j++)
                bf[j] = *(const short8*)&Wlds[kc * 4096 + (wn * 64 + j * 16 + l15) * 32 + quad * 8];
#pragma unroll
            for (int i = 0; i < 4; i++)
#pragma unroll
                for (int j = 0; j < 4; j++)
                    acc[i][j] =
                        __builtin_amdgcn_mfma_f32_16x16x32_bf16(bf[j], af[i], acc[i][j], 0, 0, 0);
        }
        __syncthreads();
    }
    // acc[i][j] is C^T-layout: D rows = n (quad*4+reg within j-tile), cols = m (l15)
#pragma unroll
    for (int i = 0; i < 4; i++) {
        int r = row0 + wm * 64 + i * 16 + l15;
#pragma unroll
        for (int j = 0; j < 4; j++) {
            int cb = col0 + wn * 64 + j * 16 + quad * 4;
            float4 bv = bias ? *(const float4*)(bias + cb) : make_float4(0.f, 0.f, 0.f, 0.f);
            float v0 = acc[i][j][0] + bv.x;
            float v1 = acc[i][j][1] + bv.y;
            float v2 = acc[i][j][2] + bv.z;
            float v3 = acc[i][j][3] + bv.w;
            if (act == 1) {
                v0 = gelu_tanh(v0); v1 = gelu_tanh(v1);
                v2 = gelu_tanh(v2); v3 = gelu_tanh(v3);
            }
            if (res) {
                uint2 rv = *(const uint2*)(res + (size_t)r * ldc + cb);
                const unsigned short* rs = (const unsigned short*)&rv;
                v0 += bf2f(rs[0]); v1 += bf2f(rs[1]);
                v2 += bf2f(rs[2]); v3 += bf2f(rs[3]);
            }
            ushort4 u;
            u.x = f2bf(v0); u.y = f2bf(v1); u.z = f2bf(v2); u.w = f2bf(v3);
            *(ushort4*)(C + (size_t)r * ldc + cb) = u;
        }
    }
}

// MFMA flash attention v5: no-max softmax (p = exp2(s), Q pre-scaled), VT
// pre-transposed in global. K/VT staged via global_load_lds (XOR-swizzled
// source, linear dest, swizzled frag reads), double-buffered, ONE barrier
// per tile. P packed in-register via v_cvt_pk_bf16_f32 into key-major
// Pt[key][16] (b64 writes), read back as PV B-frags via ds_read_b64_tr_b16.
// Row-sums l via ones-operand MFMA (D[i][j] = sum_k P[j][k]).
__global__ __launch_bounds__(256, 3) void k_attn(const unsigned short* __restrict__ qkv,
                                                 const unsigned short* __restrict__ vt,
                                                 unsigned short* __restrict__ attn) {
    __shared__ unsigned short Klds[2][64 * 64];  // 16 KB: [buf][key][dim] (swizzled slots)
    __shared__ unsigned short VTl[2][64 * 64];   // 16 KB: [buf][dim][key] (swizzled slots)
    __shared__ unsigned short Pt[4][2048];       // 16 KB: per wave, [qt][key][16 qrow]
    int b = blockIdx.z, h = blockIdx.y;
    int tid = threadIdx.x;
    int wv = tid >> 6, lane = tid & 63;
    int l15 = lane & 15, quad = lane >> 4;
    int qbase = blockIdx.x * 128 + wv * 32;
    const unsigned short* qkvb = qkv + (size_t)b * NPTS * 1152;
    const unsigned short* vtb = vt + (size_t)(b * NHEAD + h) * 64 * NPTS;
    const float SC = 0.18033688011112042f;  // 0.125 * log2(e)
    short8 qf[2][2];
#pragma unroll
    for (int qt = 0; qt < 2; qt++) {
        const unsigned short* qptr =
            qkvb + (size_t)(qbase + qt * 16 + l15) * 1152 + h * 64 + quad * 8;
        qf[qt][0] = *(const short8*)qptr;
        qf[qt][1] = *(const short8*)(qptr + 32);
#pragma unroll
        for (int g = 0; g < 2; g++) {  // fold softmax scale into Q once
            short8 v = qf[qt][g];
#pragma unroll
            for (int e = 0; e < 8; e++)
                v[e] = (short)f2bf(bf2f((unsigned short)v[e]) * SC);
            qf[qt][g] = v;
        }
    }
    short8 ones;
#pragma unroll
    for (int e = 0; e < 8; e++) ones[e] = (short)0x3F80;  // bf16 1.0
    int x7 = l15 & 7;
    int sk0 = ((quad ^ x7) << 4);        // swizzled byte slot, k-dims 0..31
    int sk1 = (((quad + 4) ^ x7) << 4);  // swizzled byte slot, k-dims 32..63
    unsigned pa = (unsigned)(size_t)(__attribute__((address_space(3))) unsigned short*)&Pt[wv][0] +
                  (unsigned)(quad * 256 + l15 * 2);
    int sdg = tid & 7;                   // staging: 16B slot within row
    floatx4 o[2][4];
#pragma unroll
    for (int qt = 0; qt < 2; qt++)
#pragma unroll
        for (int ct = 0; ct < 4; ct++) o[qt][ct] = (floatx4){0.f, 0.f, 0.f, 0.f};
    floatx4 l4[2];
    l4[0] = (floatx4){0.f, 0.f, 0.f, 0.f};
    l4[1] = (floatx4){0.f, 0.f, 0.f, 0.f};

    auto stage = [&](int c, int k0) {
#pragma unroll
        for (int i = 0; i < 2; i++) {
            int id = i * 256 + tid;
            int row = id >> 3;
            int sl = sdg ^ (row & 7);  // inverse-swizzled global slot
            gload_lds16(qkvb + (size_t)(k0 + row) * 1152 + 384 + h * 64 + sl * 8,
                        &Klds[c][(size_t)(i * 256 + (tid & 192)) * 8]);
            gload_lds16(vtb + (size_t)row * NPTS + k0 + sl * 8,
                        &VTl[c][(size_t)(i * 256 + (tid & 192)) * 8]);
        }
    };

    stage(0, 0);
    __syncthreads();
    for (int t = 0; t < 32; ++t) {
        int c = t & 1;
        if (t < 31) stage(c ^ 1, (t + 1) * 64);  // async DMA under compute
        const char* Kb = (const char*)&Klds[c][0];
        const char* Vb = (const char*)&VTl[c][0];
        short8 kf[4][2];
#pragma unroll
        for (int ct = 0; ct < 4; ct++) {
            kf[ct][0] = *(const short8*)(Kb + (ct * 16 + l15) * 128 + sk0);
            kf[ct][1] = *(const short8*)(Kb + (ct * 16 + l15) * 128 + sk1);
        }
#pragma unroll
        for (int qt = 0; qt < 2; qt++) {
            floatx4 s4[4];
#pragma unroll
            for (int ct = 0; ct < 4; ct++) {
                floatx4 z = (floatx4){0.f, 0.f, 0.f, 0.f};
                z = __builtin_amdgcn_mfma_f32_16x16x32_bf16(qf[qt][0], kf[ct][0], z, 0, 0, 0);
                z = __builtin_amdgcn_mfma_f32_16x16x32_bf16(qf[qt][1], kf[ct][1], z, 0, 0, 0);
                s4[ct] = z;
            }
#pragma unroll
            for (int ct = 0; ct < 4; ct++) {
                float p0 = __builtin_amdgcn_exp2f(s4[ct][0]);
                float p1 = __builtin_amdgcn_exp2f(s4[ct][1]);
                float p2 = __builtin_amdgcn_exp2f(s4[ct][2]);
                float p3 = __builtin_amdgcn_exp2f(s4[ct][3]);
                u32x2 pk;
                pk.x = cvtpk(p0, p1);
                pk.y = cvtpk(p2, p3);
                *(u32x2*)&Pt[wv][qt * 1024 + (ct * 16 + l15) * 16 + quad * 4] = pk;
            }
        }
        short8 vf[4][2];
#pragma unroll
        for (int ct = 0; ct < 4; ct++) {
            vf[ct][0] = *(const short8*)(Vb + (ct * 16 + l15) * 128 + sk0);
            vf[ct][1] = *(const short8*)(Vb + (ct * 16 + l15) * 128 + sk1);
        }
        asm volatile("s_waitcnt lgkmcnt(0)" ::: "memory");  // Pt writes done
        u32x2 q0g0l, q0g0h, q0g1l, q0g1h, q1g0l, q1g0h, q1g1l, q1g1h;
        TR16(q0g0l, pa, 0);
        TR16(q0g0h, pa, 128);
        TR16(q0g1l, pa, 1024);
        TR16(q0g1h, pa, 1152);
        TR16(q1g0l, pa, 2048);
        TR16(q1g0h, pa, 2176);
        TR16(q1g1l, pa, 3072);
        TR16(q1g1h, pa, 3200);
        asm volatile("s_waitcnt lgkmcnt(0)" ::: "memory");
        __builtin_amdgcn_sched_barrier(0);  // keep MFMAs below the tr reads
        short8 pf[2][2];
        pf[0][0] = __builtin_bit_cast(short8, (u32x4){q0g0l.x, q0g0l.y, q0g0h.x, q0g0h.y});
        pf[0][1] = __builtin_bit_cast(short8, (u32x4){q0g1l.x, q0g1l.y, q0g1h.x, q0g1h.y});
        pf[1][0] = __builtin_bit_cast(short8, (u32x4){q1g0l.x, q1g0l.y, q1g0h.x, q1g0h.y});
        pf[1][1] = __builtin_bit_cast(short8, (u32x4){q1g1l.x, q1g1l.y, q1g1h.x, q1g1h.y});
#pragma unroll
        for (int ct = 0; ct < 4; ct++) {
#pragma unroll
            for (int qt = 0; qt < 2; qt++) {
                o[qt][ct] = __builtin_amdgcn_mfma_f32_16x16x32_bf16(vf[ct][0], pf[qt][0], o[qt][ct], 0, 0, 0);
                o[qt][ct] = __builtin_amdgcn_mfma_f32_16x16x32_bf16(vf[ct][1], pf[qt][1], o[qt][ct], 0, 0, 0);
            }
        }
#pragma unroll
        for (int qt = 0; qt < 2; qt++) {
            l4[qt] = __builtin_amdgcn_mfma_f32_16x16x32_bf16(ones, pf[qt][0], l4[qt], 0, 0, 0);
            l4[qt] = __builtin_amdgcn_mfma_f32_16x16x32_bf16(ones, pf[qt][1], l4[qt], 0, 0, 0);
        }
        if (t < 31) __syncthreads();  // next tile's DMA + this tile's readers done
    }
#pragma unroll
    for (int qt = 0; qt < 2; qt++) {
        float linv = 1.0f / l4[qt][0];
#pragma unroll
        for (int ct = 0; ct < 4; ct++) {
            ushort4 u;
            u.x = f2bf(o[qt][ct][0] * linv);
            u.y = f2bf(o[qt][ct][1] * linv);
            u.z = f2bf(o[qt][ct][2] * linv);
            u.w = f2bf(o[qt][ct][3] * linv);
            *(ushort4*)(attn + ((size_t)b * NPTS + qbase + qt * 16 + l15) * 384 + h * 64 +
                        ct * 16 + quad * 4) = u;
        }
    }
}

// Graph attention: gq/nk/nv are column-slices of GAP [M,1152]. One wave per point.
// Writes geom into CAT[:, 384:768] (row stride 768).
__global__ __launch_bounds__(64) void k_geom(const unsigned short* __restrict__ gap,
                                             const int* __restrict__ idx,
                                             unsigned short* __restrict__ cat) {
    int r = blockIdx.x;
    int b = r >> 11;
    int t = threadIdx.x;
    int nb[8];
#pragma unroll
    for (int k = 0; k < 8; k++) nb[k] = idx[(size_t)r * 8 + k];
    const unsigned short* gqr = gap + (size_t)r * 1152;
    float qv[6];
#pragma unroll
    for (int j = 0; j < 6; j++) qv[j] = bf2f(gqr[t + 64 * j]);
    float s[8];
#pragma unroll
    for (int k = 0; k < 8; k++) {
        const unsigned short* nkr = gap + ((size_t)b * NPTS + nb[k]) * 1152 + 384;
        float acc = 0.0f;
#pragma unroll
        for (int j = 0; j < 6; j++) acc += qv[j] * bf2f(nkr[t + 64 * j]);
#pragma unroll
        for (int mm = 32; mm > 0; mm >>= 1) acc += __shfl_xor(acc, mm, 64);
        s[k] = acc * 0.05103103630798287f;  // 1/sqrt(384)
    }
    float mx = s[0];
#pragma unroll
    for (int k = 1; k < 8; k++) mx = fmaxf(mx, s[k]);
    float w[8];
    float sum = 0.0f;
#pragma unroll
    for (int k = 0; k < 8; k++) { w[k] = __expf(s[k] - mx); sum += w[k]; }
    float inv = 1.0f / sum;
    unsigned short* outr = cat + (size_t)r * 768 + 384;
#pragma unroll
    for (int j = 0; j < 6; j++) {
        int d = t + 64 * j;
        float acc = 0.0f;
#pragma unroll
        for (int k = 0; k < 8; k++)
            acc += w[k] * bf2f(gap[((size_t)b * NPTS + nb[k]) * 1152 + 768 + d]);
        outr[d] = f2bf(acc * inv);
    }
}

extern "C" void kernel_launch(void* const* d_in, const int* in_sizes, int n_in,
                              void* d_out, int out_size, void* d_ws, size_t ws_size,
                              hipStream_t stream) {
    (void)in_sizes; (void)n_in; (void)out_size; (void)ws_size;
    const float* coords     = (const float*)d_in[0];
    const float* features   = (const float*)d_in[1];
    const float* ln1_g      = (const float*)d_in[2];
    const float* ln1_b      = (const float*)d_in[3];
    const float* w_qkv      = (const float*)d_in[4];
    const float* w_attn_out = (const float*)d_in[5];
    const float* b_attn_out = (const float*)d_in[6];
    const float* ga_wq      = (const float*)d_in[7];
    const float* ga_wk      = (const float*)d_in[8];
    const float* ga_wv      = (const float*)d_in[9];
    const float* merge_w    = (const float*)d_in[10];
    const float* merge_b    = (const float*)d_in[11];
    const float* ln2_g      = (const float*)d_in[12];
    const float* ln2_b      = (const float*)d_in[13];
    const float* ff_w1      = (const float*)d_in[14];
    const float* ff_b1      = (const float*)d_in[15];
    const float* ff_w2      = (const float*)d_in[16];
    const float* ff_b2      = (const float*)d_in[17];

    // Workspace (bf16 units of SZ = 6,291,456 elems = 12 MiB). Overlay schedule:
    //   u0 F | u1 NF->HB | u2-4 QKV -> (CAT=u2-3, GAP=u4-6 after attn/AO) |
    //   u5 ATTN | u6 VT (dead before GAP gemm) | F2=u4 after geom | T1=u5-6 |
    //   FFIN=u2 | IDX + transposed weights after u7 (~4.3 MB). Peak ~100 MiB.
    unsigned short* W0 = (unsigned short*)d_ws;
    const size_t SZ = (size_t)BATCH * NPTS * D_MODEL;  // 6291456
    unsigned short* F    = W0 + 0 * SZ;
    unsigned short* NF   = W0 + 1 * SZ;
    unsigned short* QKV  = W0 + 2 * SZ;   // 3 units
    unsigned short* ATTN = W0 + 5 * SZ;
    unsigned short* VT   = W0 + 6 * SZ;   // [B,H,64,NPTS] = 1 unit
    unsigned short* CAT  = W0 + 2 * SZ;   // 2 units [M,768]
    unsigned short* GAP  = W0 + 4 * SZ;   // 3 units [M,1152]
    unsigned short* F2   = W0 + 4 * SZ;   // after GAP dead
    unsigned short* HB   = W0 + 1 * SZ;
    unsigned short* T1   = W0 + 5 * SZ;   // 2 units [M,768]
    unsigned short* FFIN = W0 + 2 * SZ;
    int*            IDX  = (int*)(W0 + 7 * SZ);
    unsigned short* WTS  = W0 + 7 * SZ + 262144;  // after IDX (512 KB)
    unsigned short* qkvT = WTS;                     // [1152,384]
    unsigned short* aoT  = qkvT + 442368;           // [384,384]
    unsigned short* gaT  = aoT + 147456;            // [1152,384]
    unsigned short* mT   = gaT + 442368;            // [384,768]
    unsigned short* f1T  = mT + 294912;             // [768,384]
    unsigned short* f2T  = f1T + 294912;            // [384,768]

    const int M = BATCH * NPTS;  // 16384

    k_wprep<<<1872, dim3(32, 8), 0, stream>>>(w_qkv, w_attn_out, ga_wq, ga_wk, ga_wv,
                                              merge_w, ff_w1, ff_w2,
                                              qkvT, aoT, gaT, mT, f1T, f2T);
    k_transpose_in<<<dim3(NPTS / 32, D_MODEL / 32, BATCH), dim3(32, 8), 0, stream>>>(features, F);
    k_layernorm<<<M, 128, 0, stream>>>(F, ln1_g, ln1_b, NF);
    k_knn<<<BATCH * (NPTS / 32), 256, 0, stream>>>(coords, IDX);
    // QKV = NF @ w_qkv
    k_gemm<<<dim3(9, M / 128), 256, 0, stream>>>(NF, 384, qkvT, nullptr, nullptr,
                                                 QKV, 1152, 384, 0);
    k_vt<<<dim3(NPTS / 32, 2 * NHEAD, BATCH), dim3(32, 8), 0, stream>>>(QKV, VT);
    k_attn<<<dim3(NPTS / 128, NHEAD, BATCH), 256, 0, stream>>>(QKV, VT, ATTN);
    // CAT[:, :384] = ATTN @ w_attn_out + b_attn_out
    k_gemm<<<dim3(3, M / 128), 256, 0, stream>>>(ATTN, 384, aoT, b_attn_out, nullptr,
                                                 CAT, 768, 384, 0);
    // GAP = NF @ [ga_wq | ga_wk | ga_wv]
    k_gemm<<<dim3(9, M / 128), 256, 0, stream>>>(NF, 384, gaT, nullptr, nullptr,
                                                 GAP, 1152, 384, 0);
    k_geom<<<M, 64, 0, stream>>>(GAP, IDX, CAT);
    // F2 = CAT @ merge_w + merge_b + F
    k_gemm<<<dim3(3, M / 128), 256, 0, stream>>>(CAT, 768, mT, merge_b, F,
                                                 F2, 384, 768, 0);
    k_layernorm<<<M, 128, 0, stream>>>(F2, ln2_g, ln2_b, HB);
    // T1 = gelu(HB @ ff_w1 + ff_b1)
    k_gemm<<<dim3(6, M / 128), 256, 0, stream>>>(HB, 384, f1T, ff_b1, nullptr,
                                                 T1, 768, 384, 1);
    // FFIN = F2 + T1 @ ff_w2 + ff_b2
    k_gemm<<<dim3(3, M / 128), 256, 0, stream>>>(T1, 768, f2T, ff_b2, F2,
                                                 FFIN, 384, 768, 0);
    k_transpose_out<<<dim3(D_MODEL / 32, NPTS / 32, BATCH), dim3(32, 8), 0, stream>>>(
        FFIN, (float*)d_out);
}

// Round 4
// 480.722 us; speedup vs baseline: 1.1474x; 1.0543x over previous
//
#include <hip/hip_runtime.h>
#include <hip/hip_bf16.h>
#include <cstdint>

#define D_MODEL 384
#define NHEAD 6
#define DHEAD 64
#define NPTS 2048
#define BATCH 8

typedef __attribute__((ext_vector_type(8))) short short8;
typedef __attribute__((ext_vector_type(4))) float floatx4;
typedef __attribute__((ext_vector_type(2))) unsigned int u32x2;
typedef __attribute__((ext_vector_type(4))) unsigned int u32x4;

__device__ __forceinline__ float bf2f(unsigned short u) {
    return __uint_as_float(((unsigned int)u) << 16);
}

// round-to-nearest-even f32 -> bf16 (finite inputs only)
__device__ __forceinline__ unsigned short f2bf(float f) {
    unsigned int u = __float_as_uint(f);
    unsigned int r = (u + 0x7FFFu + ((u >> 16) & 1u)) >> 16;
    return (unsigned short)r;
}

// v_cvt_pk_bf16_f32: pack two f32 -> {bf16(lo), bf16(hi)} in one u32 (RNE)
__device__ __forceinline__ unsigned cvtpk(float lo, float hi) {
    unsigned r;
    asm("v_cvt_pk_bf16_f32 %0, %1, %2" : "=v"(r) : "v"(lo), "v"(hi));
    return r;
}

// ds_read_b64_tr_b16: per-lane gather of 4 bf16 at addr + j*16 elems (j=0..3)
#define TR16(dst, addr, imm) \
    asm volatile("ds_read_b64_tr_b16 %0, %1 offset:" #imm : "=v"(dst) : "v"(addr))

__device__ __forceinline__ float gelu_tanh(float x) {
    float x3 = x * x * x;
    return 0.5f * x * (1.0f + tanhf(0.7978845608028654f * (x + 0.044715f * x3)));
}

// async 16B global -> LDS (wave-uniform LDS base + lane*16)
__device__ __forceinline__ void gload_lds16(const unsigned short* g, unsigned short* l) {
    __builtin_amdgcn_global_load_lds(
        (const __attribute__((address_space(1))) unsigned int*)g,
        (__attribute__((address_space(3))) unsigned int*)l, 16, 0, 0);
}

// Weight prep: fp32 [K,N] -> bf16 [N,K] (transposed), all 8 weights in one dispatch.
__global__ __launch_bounds__(256) void k_wprep(
    const float* __restrict__ wqkv, const float* __restrict__ wao,
    const float* __restrict__ wq, const float* __restrict__ wk,
    const float* __restrict__ wv, const float* __restrict__ wm,
    const float* __restrict__ w1, const float* __restrict__ w2,
    unsigned short* __restrict__ qkvT, unsigned short* __restrict__ aoT,
    unsigned short* __restrict__ gaT, unsigned short* __restrict__ mT,
    unsigned short* __restrict__ f1T, unsigned short* __restrict__ f2T) {
    __shared__ float tile[32][33];
    int id = blockIdx.x;
    const float* src;
    unsigned short* dst;
    int K, N;
    if (id < 432)       {            src = wqkv; dst = qkvT;            K = 384; N = 1152; }
    else if (id < 576)  { id -= 432; src = wao;  dst = aoT;             K = 384; N = 384; }
    else if (id < 720)  { id -= 576; src = wq;   dst = gaT;             K = 384; N = 384; }
    else if (id < 864)  { id -= 720; src = wk;   dst = gaT + 384 * 384; K = 384; N = 384; }
    else if (id < 1008) { id -= 864; src = wv;   dst = gaT + 768 * 384; K = 384; N = 384; }
    else if (id < 1296) { id -= 1008; src = wm;  dst = mT;              K = 768; N = 384; }
    else if (id < 1584) { id -= 1296; src = w1;  dst = f1T;             K = 384; N = 768; }
    else                { id -= 1584; src = w2;  dst = f2T;             K = 768; N = 384; }
    int ntiles = N >> 5;
    int nt = id % ntiles, kt = id / ntiles;
    int tx = threadIdx.x, ty = threadIdx.y;
#pragma unroll
    for (int i = 0; i < 32; i += 8)
        tile[ty + i][tx] = src[(size_t)(kt * 32 + ty + i) * N + nt * 32 + tx];
    __syncthreads();
#pragma unroll
    for (int i = 0; i < 32; i += 8)
        dst[(size_t)(nt * 32 + ty + i) * K + kt * 32 + tx] = f2bf(tile[tx][ty + i]);
}

// features fp32 [B, D, N] -> F bf16 [B, N, D]
__global__ __launch_bounds__(256) void k_transpose_in(const float* __restrict__ feat,
                                                      unsigned short* __restrict__ f) {
    __shared__ float tile[32][33];
    int b = blockIdx.z;
    int n0 = blockIdx.x * 32, d0 = blockIdx.y * 32;
    int tx = threadIdx.x, ty = threadIdx.y;
#pragma unroll
    for (int i = 0; i < 32; i += 8)
        tile[ty + i][tx] = feat[((size_t)b * D_MODEL + d0 + ty + i) * NPTS + n0 + tx];
    __syncthreads();
#pragma unroll
    for (int i = 0; i < 32; i += 8)
        f[((size_t)b * NPTS + n0 + ty + i) * D_MODEL + d0 + tx] = f2bf(tile[tx][ty + i]);
}

// FFIN bf16 [B, N, D] -> out fp32 [B, D, N]
__global__ __launch_bounds__(256) void k_transpose_out(const unsigned short* __restrict__ f,
                                                       float* __restrict__ out) {
    __shared__ float tile[32][33];
    int b = blockIdx.z;
    int d0 = blockIdx.x * 32, n0 = blockIdx.y * 32;
    int tx = threadIdx.x, ty = threadIdx.y;
#pragma unroll
    for (int i = 0; i < 32; i += 8)
        tile[ty + i][tx] = bf2f(f[((size_t)b * NPTS + n0 + ty + i) * D_MODEL + d0 + tx]);
    __syncthreads();
#pragma unroll
    for (int i = 0; i < 32; i += 8)
        out[((size_t)b * D_MODEL + d0 + ty + i) * NPTS + n0 + tx] = tile[tx][ty + i];
}

// V slice of QKV [M,1152] (cols 768..1152) -> VT [B,H,64,NPTS]
__global__ __launch_bounds__(256) void k_vt(const unsigned short* __restrict__ qkv,
                                            unsigned short* __restrict__ vt) {
    __shared__ unsigned short tile[32][33];
    int b = blockIdx.z;
    int h = blockIdx.y >> 1, d0 = (blockIdx.y & 1) * 32;
    int n0 = blockIdx.x * 32;
    int tx = threadIdx.x, ty = threadIdx.y;
#pragma unroll
    for (int i = 0; i < 32; i += 8)
        tile[ty + i][tx] =
            qkv[((size_t)b * NPTS + n0 + ty + i) * 1152 + 768 + h * 64 + d0 + tx];
    __syncthreads();
#pragma unroll
    for (int i = 0; i < 32; i += 8)
        vt[(((size_t)(b * NHEAD + h) * 64) + d0 + ty + i) * NPTS + n0 + tx] = tile[tx][ty + i];
}

// LayerNorm over D=384 (bf16 in/out, fp32 g/b), one block (128 thr) per row
__global__ __launch_bounds__(128) void k_layernorm(const unsigned short* __restrict__ x,
                                                   const float* __restrict__ g,
                                                   const float* __restrict__ bt,
                                                   unsigned short* __restrict__ y) {
    int row = blockIdx.x, t = threadIdx.x;
    const unsigned short* xr = x + (size_t)row * D_MODEL;
    float v0 = bf2f(xr[t]), v1 = bf2f(xr[t + 128]), v2 = bf2f(xr[t + 256]);
    float s = v0 + v1 + v2;
    float s2 = v0 * v0 + v1 * v1 + v2 * v2;
#pragma unroll
    for (int off = 32; off > 0; off >>= 1) {
        s += __shfl_xor(s, off, 64);
        s2 += __shfl_xor(s2, off, 64);
    }
    __shared__ float ps[2], ps2[2];
    if ((t & 63) == 0) { ps[t >> 6] = s; ps2[t >> 6] = s2; }
    __syncthreads();
    s = ps[0] + ps[1];
    s2 = ps2[0] + ps2[1];
    float mean = s * (1.0f / 384.0f);
    float var = s2 * (1.0f / 384.0f) - mean * mean;
    var = fmaxf(var, 0.0f);
    float inv = 1.0f / sqrtf(var + 1e-5f);
    unsigned short* yr = y + (size_t)row * D_MODEL;
    yr[t]       = f2bf((v0 - mean) * inv * g[t]       + bt[t]);
    yr[t + 128] = f2bf((v1 - mean) * inv * g[t + 128] + bt[t + 128]);
    yr[t + 256] = f2bf((v2 - mean) * inv * g[t + 256] + bt[t + 256]);
}

// KNN v2: one wave per query. 64 lanes x 32 candidates each, per-lane sorted
// top-8 (u64 keys: ordered-float d2 in high bits, index in low bits -> unique,
// top_k tie-break preserved). Merge = 8 rounds of 64-lane u64-min butterfly;
// winner pops via static shift (keys unique => exactly one cur==w).
__global__ __launch_bounds__(256) void k_knn(const float* __restrict__ coords,
                                             int* __restrict__ idx) {
    __shared__ float4 cpts[NPTS];
    int b = blockIdx.x >> 9;             // 512 blocks per batch
    int q0 = (blockIdx.x & 511) * 4;     // 4 queries (waves) per block
    const float* cb = coords + (size_t)b * 3 * NPTS;
    int tid = threadIdx.x;
#pragma unroll
    for (int i = 0; i < 8; i++) {
        int m = tid + i * 256;
        float x = cb[m], y = cb[NPTS + m], z = cb[2 * NPTS + m];
        float sq = __fadd_rn(__fadd_rn(__fmul_rn(x, x), __fmul_rn(y, y)), __fmul_rn(z, z));
        cpts[m] = make_float4(x, y, z, sq);
    }
    __syncthreads();
    int wv = tid >> 6, lane = tid & 63;
    int n = q0 + wv;
    float4 qp = cpts[n];
    float qx = qp.x, qy = qp.y, qz = qp.z, sqn = qp.w;
    unsigned long long heap[8];
#pragma unroll
    for (int k = 0; k < 8; k++) heap[k] = 0xFFFFFFFFFFFFFFFFull;
    for (int j = 0; j < 32; j++) {
        int m = j * 64 + lane;
        float4 cp = cpts[m];
        float dot = __fadd_rn(__fadd_rn(__fmul_rn(qx, cp.x), __fmul_rn(qy, cp.y)),
                              __fmul_rn(qz, cp.z));
        float d2 = __fsub_rn(__fadd_rn(sqn, cp.w), __fmul_rn(2.0f, dot));
        unsigned int u = __float_as_uint(d2);
        u = (u & 0x80000000u) ? ~u : (u | 0x80000000u);
        unsigned long long key = ((unsigned long long)u << 32) | (unsigned int)m;
        if (key < heap[7]) {  // straight-line insert network (8 min/max stages)
            unsigned long long cur = key;
#pragma unroll
            for (int t2 = 0; t2 < 8; t2++) {
                unsigned long long h = heap[t2];
                unsigned long long lo = h < cur ? h : cur;
                cur = h < cur ? cur : h;
                heap[t2] = lo;
            }
        }
    }
    unsigned long long cur = heap[0];
    unsigned int out[8];
#pragma unroll
    for (int r = 0; r < 8; r++) {
        unsigned long long w = cur;
#pragma unroll
        for (int off = 1; off < 64; off <<= 1) {
            unsigned long long o = __shfl_xor(w, off, 64);
            w = o < w ? o : w;
        }
        out[r] = (unsigned int)(w & 0xFFFFFFFFu);
        if (cur == w) {  // unique winner: pop my head
#pragma unroll
            for (int t2 = 0; t2 < 7; t2++) heap[t2] = heap[t2 + 1];
            heap[7] = 0xFFFFFFFFFFFFFFFFull;
            cur = heap[0];
        }
    }
    if (lane == 0) {
        unsigned int* outr = (unsigned int*)(idx + ((size_t)b * NPTS + n) * 8);
        *(uint4*)outr = make_uint4(out[0], out[1], out[2], out[3]);
        *(uint4*)(outr + 4) = make_uint4(out[4], out[5], out[6], out[7]);
    }
}

// MFMA GEMM v5: 128x128 tile, BK=64. BOTH operands staged to LDS via async
// global_load_lds (16B, zero staging VALU), layout = two 128x32 chunks per
// operand (pitch 64B, proven v3 bank pattern). Operand-swapped MFMA
// (acc = W_frag x A_frag = C^T layout) so the epilogue's 4 acc regs per lane
// are contiguous columns -> ushort4 stores, uint2 res loads, float4 bias.
// A bf16 [M,K] (lda), WT bf16 [N,K], bias fp32, res/C bf16 (ldc).
__global__ __launch_bounds__(256) void k_gemm(const unsigned short* __restrict__ A, int lda,
                                              const unsigned short* __restrict__ WT,
                                              const float* __restrict__ bias,
                                              const unsigned short* __restrict__ res,
                                              unsigned short* __restrict__ C, int ldc,
                                              int K, int act) {
    __shared__ unsigned short Alds[2 * 128 * 32];  // 16 KB: [kc][row][32]
    __shared__ unsigned short Wlds[2 * 128 * 32];  // 16 KB: [kc][nrow][32]
    int tid = threadIdx.x;
    int wv = tid >> 6, lane = tid & 63;
    int l15 = lane & 15, quad = lane >> 4;
    int row0 = blockIdx.y * 128, col0 = blockIdx.x * 128;
    int wm = wv >> 1, wn = wv & 1;
    int wbase = tid & 192;  // wv*64
    floatx4 acc[4][4];
#pragma unroll
    for (int i = 0; i < 4; i++)
#pragma unroll
        for (int j = 0; j < 4; j++) acc[i][j] = (floatx4){0.f, 0.f, 0.f, 0.f};
    for (int k0 = 0; k0 < K; k0 += 64) {
#pragma unroll
        for (int i = 0; i < 4; i++) {
            int idx = i * 256 + tid;
            int kc = idx >> 9, row = (idx >> 2) & 127, ko = idx & 3;
            unsigned short* ldst = Alds + (size_t)(i * 256 + wbase) * 8;  // idx*16B, wave-uniform
            gload_lds16(A + (size_t)(row0 + row) * lda + k0 + kc * 32 + ko * 8, ldst);
            unsigned short* ldstw = Wlds + (size_t)(i * 256 + wbase) * 8;
            gload_lds16(WT + (size_t)(col0 + row) * K + k0 + kc * 32 + ko * 8, ldstw);
        }
        __syncthreads();  // drains global_load_lds
#pragma unroll
        for (int kc = 0; kc < 2; kc++) {
            short8 af[4], bf[4];
#pragma unroll
            for (int i = 0; i < 4; i++)
                af[i] = *(const short8*)&Alds[kc * 4096 + (wm * 64 + i * 16 + l15) * 32 + quad * 8];
#pragma unroll
            for (int j = 0; j < 4; j++)
                bf[j] = *(const short8*)&Wlds[kc * 4096 + (wn * 64 + j * 16 + l15) * 32 + quad * 8];
#pragma unroll
            for (int i = 0; i < 4; i++)
#pragma unroll
                for (int j = 0; j < 4; j++)
                    acc[i][j] =
                        __builtin_amdgcn_mfma_f32_16x16x32_bf16(bf[j], af[i], acc[i][j], 0, 0, 0);
        }
        __syncthreads();
    }
    // acc[i][j] is C^T-layout: D rows = n (quad*4+reg within j-tile), cols = m (l15)
#pragma unroll
    for (int i = 0; i < 4; i++) {
        int r = row0 + wm * 64 + i * 16 + l15;
#pragma unroll
        for (int j = 0; j < 4; j++) {
            int cb = col0 + wn * 64 + j * 16 + quad * 4;
            float4 bv = bias ? *(const float4*)(bias + cb) : make_float4(0.f, 0.f, 0.f, 0.f);
            float v0 = acc[i][j][0] + bv.x;
            float v1 = acc[i][j][1] + bv.y;
            float v2 = acc[i][j][2] + bv.z;
            float v3 = acc[i][j][3] + bv.w;
            if (act == 1) {
                v0 = gelu_tanh(v0); v1 = gelu_tanh(v1);
                v2 = gelu_tanh(v2); v3 = gelu_tanh(v3);
            }
            if (res) {
                uint2 rv = *(const uint2*)(res + (size_t)r * ldc + cb);
                const unsigned short* rs = (const unsigned short*)&rv;
                v0 += bf2f(rs[0]); v1 += bf2f(rs[1]);
                v2 += bf2f(rs[2]); v3 += bf2f(rs[3]);
            }
            ushort4 u;
            u.x = f2bf(v0); u.y = f2bf(v1); u.z = f2bf(v2); u.w = f2bf(v3);
            *(ushort4*)(C + (size_t)r * ldc + cb) = u;
        }
    }
}

// MFMA flash attention v5: no-max softmax (p = exp2(s), Q pre-scaled), VT
// pre-transposed in global. K/VT staged via global_load_lds (XOR-swizzled
// source, linear dest, swizzled frag reads), double-buffered, ONE barrier
// per tile. P packed in-register via v_cvt_pk_bf16_f32 into key-major
// Pt[key][16] (b64 writes), read back as PV B-frags via ds_read_b64_tr_b16.
// Row-sums l via ones-operand MFMA (D[i][j] = sum_k P[j][k]).
__global__ __launch_bounds__(256, 3) void k_attn(const unsigned short* __restrict__ qkv,
                                                 const unsigned short* __restrict__ vt,
                                                 unsigned short* __restrict__ attn) {
    __shared__ unsigned short Klds[2][64 * 64];  // 16 KB: [buf][key][dim] (swizzled slots)
    __shared__ unsigned short VTl[2][64 * 64];   // 16 KB: [buf][dim][key] (swizzled slots)
    __shared__ unsigned short Pt[4][2048];       // 16 KB: per wave, [qt][key][16 qrow]
    int b = blockIdx.z, h = blockIdx.y;
    int tid = threadIdx.x;
    int wv = tid >> 6, lane = tid & 63;
    int l15 = lane & 15, quad = lane >> 4;
    int qbase = blockIdx.x * 128 + wv * 32;
    const unsigned short* qkvb = qkv + (size_t)b * NPTS * 1152;
    const unsigned short* vtb = vt + (size_t)(b * NHEAD + h) * 64 * NPTS;
    const float SC = 0.18033688011112042f;  // 0.125 * log2(e)
    short8 qf[2][2];
#pragma unroll
    for (int qt = 0; qt < 2; qt++) {
        const unsigned short* qptr =
            qkvb + (size_t)(qbase + qt * 16 + l15) * 1152 + h * 64 + quad * 8;
        qf[qt][0] = *(const short8*)qptr;
        qf[qt][1] = *(const short8*)(qptr + 32);
#pragma unroll
        for (int g = 0; g < 2; g++) {  // fold softmax scale into Q once
            short8 v = qf[qt][g];
#pragma unroll
            for (int e = 0; e < 8; e++)
                v[e] = (short)f2bf(bf2f((unsigned short)v[e]) * SC);
            qf[qt][g] = v;
        }
    }
    short8 ones;
#pragma unroll
    for (int e = 0; e < 8; e++) ones[e] = (short)0x3F80;  // bf16 1.0
    int x7 = l15 & 7;
    int sk0 = ((quad ^ x7) << 4);        // swizzled byte slot, k-dims 0..31
    int sk1 = (((quad + 4) ^ x7) << 4);  // swizzled byte slot, k-dims 32..63
    unsigned pa = (unsigned)(size_t)(__attribute__((address_space(3))) unsigned short*)&Pt[wv][0] +
                  (unsigned)(quad * 256 + l15 * 2);
    int sdg = tid & 7;                   // staging: 16B slot within row
    floatx4 o[2][4];
#pragma unroll
    for (int qt = 0; qt < 2; qt++)
#pragma unroll
        for (int ct = 0; ct < 4; ct++) o[qt][ct] = (floatx4){0.f, 0.f, 0.f, 0.f};
    floatx4 l4[2];
    l4[0] = (floatx4){0.f, 0.f, 0.f, 0.f};
    l4[1] = (floatx4){0.f, 0.f, 0.f, 0.f};

    auto stage = [&](int c, int k0) {
#pragma unroll
        for (int i = 0; i < 2; i++) {
            int id = i * 256 + tid;
            int row = id >> 3;
            int sl = sdg ^ (row & 7);  // inverse-swizzled global slot
            gload_lds16(qkvb + (size_t)(k0 + row) * 1152 + 384 + h * 64 + sl * 8,
                        &Klds[c][(size_t)(i * 256 + (tid & 192)) * 8]);
            gload_lds16(vtb + (size_t)row * NPTS + k0 + sl * 8,
                        &VTl[c][(size_t)(i * 256 + (tid & 192)) * 8]);
        }
    };

    stage(0, 0);
    __syncthreads();
    for (int t = 0; t < 32; ++t) {
        int c = t & 1;
        if (t < 31) stage(c ^ 1, (t + 1) * 64);  // async DMA under compute
        const char* Kb = (const char*)&Klds[c][0];
        const char* Vb = (const char*)&VTl[c][0];
        short8 kf[4][2];
#pragma unroll
        for (int ct = 0; ct < 4; ct++) {
            kf[ct][0] = *(const short8*)(Kb + (ct * 16 + l15) * 128 + sk0);
            kf[ct][1] = *(const short8*)(Kb + (ct * 16 + l15) * 128 + sk1);
        }
#pragma unroll
        for (int qt = 0; qt < 2; qt++) {
            floatx4 s4[4];
#pragma unroll
            for (int ct = 0; ct < 4; ct++) {
                floatx4 z = (floatx4){0.f, 0.f, 0.f, 0.f};
                z = __builtin_amdgcn_mfma_f32_16x16x32_bf16(qf[qt][0], kf[ct][0], z, 0, 0, 0);
                z = __builtin_amdgcn_mfma_f32_16x16x32_bf16(qf[qt][1], kf[ct][1], z, 0, 0, 0);
                s4[ct] = z;
            }
#pragma unroll
            for (int ct = 0; ct < 4; ct++) {
                float p0 = __builtin_amdgcn_exp2f(s4[ct][0]);
                float p1 = __builtin_amdgcn_exp2f(s4[ct][1]);
                float p2 = __builtin_amdgcn_exp2f(s4[ct][2]);
                float p3 = __builtin_amdgcn_exp2f(s4[ct][3]);
                u32x2 pk;
                pk.x = cvtpk(p0, p1);
                pk.y = cvtpk(p2, p3);
                *(u32x2*)&Pt[wv][qt * 1024 + (ct * 16 + l15) * 16 + quad * 4] = pk;
            }
        }
        short8 vf[4][2];
#pragma unroll
        for (int ct = 0; ct < 4; ct++) {
            vf[ct][0] = *(const short8*)(Vb + (ct * 16 + l15) * 128 + sk0);
            vf[ct][1] = *(const short8*)(Vb + (ct * 16 + l15) * 128 + sk1);
        }
        asm volatile("s_waitcnt lgkmcnt(0)" ::: "memory");  // Pt writes done
        u32x2 q0g0l, q0g0h, q0g1l, q0g1h, q1g0l, q1g0h, q1g1l, q1g1h;
        TR16(q0g0l, pa, 0);
        TR16(q0g0h, pa, 128);
        TR16(q0g1l, pa, 1024);
        TR16(q0g1h, pa, 1152);
        TR16(q1g0l, pa, 2048);
        TR16(q1g0h, pa, 2176);
        TR16(q1g1l, pa, 3072);
        TR16(q1g1h, pa, 3200);
        asm volatile("s_waitcnt lgkmcnt(0)" ::: "memory");
        __builtin_amdgcn_sched_barrier(0);  // keep MFMAs below the tr reads
        short8 pf[2][2];
        pf[0][0] = __builtin_bit_cast(short8, (u32x4){q0g0l.x, q0g0l.y, q0g0h.x, q0g0h.y});
        pf[0][1] = __builtin_bit_cast(short8, (u32x4){q0g1l.x, q0g1l.y, q0g1h.x, q0g1h.y});
        pf[1][0] = __builtin_bit_cast(short8, (u32x4){q1g0l.x, q1g0l.y, q1g0h.x, q1g0h.y});
        pf[1][1] = __builtin_bit_cast(short8, (u32x4){q1g1l.x, q1g1l.y, q1g1h.x, q1g1h.y});
#pragma unroll
        for (int ct = 0; ct < 4; ct++) {
#pragma unroll
            for (int qt = 0; qt < 2; qt++) {
                o[qt][ct] = __builtin_amdgcn_mfma_f32_16x16x32_bf16(vf[ct][0], pf[qt][0], o[qt][ct], 0, 0, 0);
                o[qt][ct] = __builtin_amdgcn_mfma_f32_16x16x32_bf16(vf[ct][1], pf[qt][1], o[qt][ct], 0, 0, 0);
            }
        }
#pragma unroll
        for (int qt = 0; qt < 2; qt++) {
            l4[qt] = __builtin_amdgcn_mfma_f32_16x16x32_bf16(ones, pf[qt][0], l4[qt], 0, 0, 0);
            l4[qt] = __builtin_amdgcn_mfma_f32_16x16x32_bf16(ones, pf[qt][1], l4[qt], 0, 0, 0);
        }
        if (t < 31) __syncthreads();  // next tile's DMA + this tile's readers done
    }
#pragma unroll
    for (int qt = 0; qt < 2; qt++) {
        float linv = 1.0f / l4[qt][0];
#pragma unroll
        for (int ct = 0; ct < 4; ct++) {
            ushort4 u;
            u.x = f2bf(o[qt][ct][0] * linv);
            u.y = f2bf(o[qt][ct][1] * linv);
            u.z = f2bf(o[qt][ct][2] * linv);
            u.w = f2bf(o[qt][ct][3] * linv);
            *(ushort4*)(attn + ((size_t)b * NPTS + qbase + qt * 16 + l15) * 384 + h * 64 +
                        ct * 16 + quad * 4) = u;
        }
    }
}

// Graph attention: gq/nk/nv are column-slices of GAP [M,1152]. One wave per point.
// Writes geom into CAT[:, 384:768] (row stride 768).
__global__ __launch_bounds__(64) void k_geom(const unsigned short* __restrict__ gap,
                                             const int* __restrict__ idx,
                                             unsigned short* __restrict__ cat) {
    int r = blockIdx.x;
    int b = r >> 11;
    int t = threadIdx.x;
    int nb[8];
#pragma unroll
    for (int k = 0; k < 8; k++) nb[k] = idx[(size_t)r * 8 + k];
    const unsigned short* gqr = gap + (size_t)r * 1152;
    float qv[6];
#pragma unroll
    for (int j = 0; j < 6; j++) qv[j] = bf2f(gqr[t + 64 * j]);
    float s[8];
#pragma unroll
    for (int k = 0; k < 8; k++) {
        const unsigned short* nkr = gap + ((size_t)b * NPTS + nb[k]) * 1152 + 384;
        float acc = 0.0f;
#pragma unroll
        for (int j = 0; j < 6; j++) acc += qv[j] * bf2f(nkr[t + 64 * j]);
#pragma unroll
        for (int mm = 32; mm > 0; mm >>= 1) acc += __shfl_xor(acc, mm, 64);
        s[k] = acc * 0.05103103630798287f;  // 1/sqrt(384)
    }
    float mx = s[0];
#pragma unroll
    for (int k = 1; k < 8; k++) mx = fmaxf(mx, s[k]);
    float w[8];
    float sum = 0.0f;
#pragma unroll
    for (int k = 0; k < 8; k++) { w[k] = __expf(s[k] - mx); sum += w[k]; }
    float inv = 1.0f / sum;
    unsigned short* outr = cat + (size_t)r * 768 + 384;
#pragma unroll
    for (int j = 0; j < 6; j++) {
        int d = t + 64 * j;
        float acc = 0.0f;
#pragma unroll
        for (int k = 0; k < 8; k++)
            acc += w[k] * bf2f(gap[((size_t)b * NPTS + nb[k]) * 1152 + 768 + d]);
        outr[d] = f2bf(acc * inv);
    }
}

extern "C" void kernel_launch(void* const* d_in, const int* in_sizes, int n_in,
                              void* d_out, int out_size, void* d_ws, size_t ws_size,
                              hipStream_t stream) {
    (void)in_sizes; (void)n_in; (void)out_size; (void)ws_size;
    const float* coords     = (const float*)d_in[0];
    const float* features   = (const float*)d_in[1];
    const float* ln1_g      = (const float*)d_in[2];
    const float* ln1_b      = (const float*)d_in[3];
    const float* w_qkv      = (const float*)d_in[4];
    const float* w_attn_out = (const float*)d_in[5];
    const float* b_attn_out = (const float*)d_in[6];
    const float* ga_wq      = (const float*)d_in[7];
    const float* ga_wk      = (const float*)d_in[8];
    const float* ga_wv      = (const float*)d_in[9];
    const float* merge_w    = (const float*)d_in[10];
    const float* merge_b    = (const float*)d_in[11];
    const float* ln2_g      = (const float*)d_in[12];
    const float* ln2_b      = (const float*)d_in[13];
    const float* ff_w1      = (const float*)d_in[14];
    const float* ff_b1      = (const float*)d_in[15];
    const float* ff_w2      = (const float*)d_in[16];
    const float* ff_b2      = (const float*)d_in[17];

    // Workspace (bf16 units of SZ = 6,291,456 elems = 12 MiB). Overlay schedule:
    //   u0 F | u1 NF->HB | u2-4 QKV -> (CAT=u2-3, GAP=u4-6 after attn/AO) |
    //   u5 ATTN | u6 VT (dead before GAP gemm) | F2=u4 after geom | T1=u5-6 |
    //   FFIN=u2 | IDX + transposed weights after u7 (~4.3 MB). Peak ~100 MiB.
    unsigned short* W0 = (unsigned short*)d_ws;
    const size_t SZ = (size_t)BATCH * NPTS * D_MODEL;  // 6291456
    unsigned short* F    = W0 + 0 * SZ;
    unsigned short* NF   = W0 + 1 * SZ;
    unsigned short* QKV  = W0 + 2 * SZ;   // 3 units
    unsigned short* ATTN = W0 + 5 * SZ;
    unsigned short* VT   = W0 + 6 * SZ;   // [B,H,64,NPTS] = 1 unit
    unsigned short* CAT  = W0 + 2 * SZ;   // 2 units [M,768]
    unsigned short* GAP  = W0 + 4 * SZ;   // 3 units [M,1152]
    unsigned short* F2   = W0 + 4 * SZ;   // after GAP dead
    unsigned short* HB   = W0 + 1 * SZ;
    unsigned short* T1   = W0 + 5 * SZ;   // 2 units [M,768]
    unsigned short* FFIN = W0 + 2 * SZ;
    int*            IDX  = (int*)(W0 + 7 * SZ);
    unsigned short* WTS  = W0 + 7 * SZ + 262144;  // after IDX (512 KB)
    unsigned short* qkvT = WTS;                     // [1152,384]
    unsigned short* aoT  = qkvT + 442368;           // [384,384]
    unsigned short* gaT  = aoT + 147456;            // [1152,384]
    unsigned short* mT   = gaT + 442368;            // [384,768]
    unsigned short* f1T  = mT + 294912;             // [768,384]
    unsigned short* f2T  = f1T + 294912;            // [384,768]

    const int M = BATCH * NPTS;  // 16384

    k_wprep<<<1872, dim3(32, 8), 0, stream>>>(w_qkv, w_attn_out, ga_wq, ga_wk, ga_wv,
                                              merge_w, ff_w1, ff_w2,
                                              qkvT, aoT, gaT, mT, f1T, f2T);
    k_transpose_in<<<dim3(NPTS / 32, D_MODEL / 32, BATCH), dim3(32, 8), 0, stream>>>(features, F);
    k_layernorm<<<M, 128, 0, stream>>>(F, ln1_g, ln1_b, NF);
    k_knn<<<BATCH * (NPTS / 4), 256, 0, stream>>>(coords, IDX);
    // QKV = NF @ w_qkv
    k_gemm<<<dim3(9, M / 128), 256, 0, stream>>>(NF, 384, qkvT, nullptr, nullptr,
                                                 QKV, 1152, 384, 0);
    k_vt<<<dim3(NPTS / 32, 2 * NHEAD, BATCH), dim3(32, 8), 0, stream>>>(QKV, VT);
    k_attn<<<dim3(NPTS / 128, NHEAD, BATCH), 256, 0, stream>>>(QKV, VT, ATTN);
    // CAT[:, :384] = ATTN @ w_attn_out + b_attn_out
    k_gemm<<<dim3(3, M / 128), 256, 0, stream>>>(ATTN, 384, aoT, b_attn_out, nullptr,
                                                 CAT, 768, 384, 0);
    // GAP = NF @ [ga_wq | ga_wk | ga_wv]
    k_gemm<<<dim3(9, M / 128), 256, 0, stream>>>(NF, 384, gaT, nullptr, nullptr,
                                                 GAP, 1152, 384, 0);
    k_geom<<<M, 64, 0, stream>>>(GAP, IDX, CAT);
    // F2 = CAT @ merge_w + merge_b + F
    k_gemm<<<dim3(3, M / 128), 256, 0, stream>>>(CAT, 768, mT, merge_b, F,
                                                 F2, 384, 768, 0);
    k_layernorm<<<M, 128, 0, stream>>>(F2, ln2_g, ln2_b, HB);
    // T1 = gelu(HB @ ff_w1 + ff_b1)
    k_gemm<<<dim3(6, M / 128), 256, 0, stream>>>(HB, 384, f1T, ff_b1, nullptr,
                                                 T1, 768, 384, 1);
    // FFIN = F2 + T1 @ ff_w2 + ff_b2
    k_gemm<<<dim3(3, M / 128), 256, 0, stream>>>(T1, 768, f2T, ff_b2, F2,
                                                 FFIN, 384, 768, 0);
    k_transpose_out<<<dim3(D_MODEL / 32, NPTS / 32, BATCH), dim3(32, 8), 0, stream>>>(
        FFIN, (float*)d_out);
}

// Round 5
// 447.503 us; speedup vs baseline: 1.2326x; 1.0742x over previous
//
#include <hip/hip_runtime.h>
#include <hip/hip_bf16.h>
#include <cstdint>

#define D_MODEL 384
#define NHEAD 6
#define DHEAD 64
#define NPTS 2048
#define BATCH 8

typedef __attribute__((ext_vector_type(8))) short short8;
typedef __attribute__((ext_vector_type(4))) float floatx4;
typedef __attribute__((ext_vector_type(2))) unsigned int u32x2;
typedef __attribute__((ext_vector_type(4))) unsigned int u32x4;

__device__ __forceinline__ float bf2f(unsigned short u) {
    return __uint_as_float(((unsigned int)u) << 16);
}

// round-to-nearest-even f32 -> bf16 (finite inputs only)
__device__ __forceinline__ unsigned short f2bf(float f) {
    unsigned int u = __float_as_uint(f);
    unsigned int r = (u + 0x7FFFu + ((u >> 16) & 1u)) >> 16;
    return (unsigned short)r;
}

// v_cvt_pk_bf16_f32: pack two f32 -> {bf16(lo), bf16(hi)} in one u32 (RNE)
__device__ __forceinline__ unsigned cvtpk(float lo, float hi) {
    unsigned r;
    asm("v_cvt_pk_bf16_f32 %0, %1, %2" : "=v"(r) : "v"(lo), "v"(hi));
    return r;
}

// ds_read_b64_tr_b16: per-lane gather of 4 bf16 at addr + j*16 elems (j=0..3)
#define TR16(dst, addr, imm) \
    asm volatile("ds_read_b64_tr_b16 %0, %1 offset:" #imm : "=v"(dst) : "v"(addr))

__device__ __forceinline__ float gelu_tanh(float x) {
    float x3 = x * x * x;
    return 0.5f * x * (1.0f + tanhf(0.7978845608028654f * (x + 0.044715f * x3)));
}

// async 16B global -> LDS (wave-uniform LDS base + lane*16)
__device__ __forceinline__ void gload_lds16(const unsigned short* g, unsigned short* l) {
    __builtin_amdgcn_global_load_lds(
        (const __attribute__((address_space(1))) unsigned int*)g,
        (__attribute__((address_space(3))) unsigned int*)l, 16, 0, 0);
}

// Weight prep: fp32 [K,N] -> bf16 [N,K] (transposed), all 8 weights in one dispatch.
__global__ __launch_bounds__(256) void k_wprep(
    const float* __restrict__ wqkv, const float* __restrict__ wao,
    const float* __restrict__ wq, const float* __restrict__ wk,
    const float* __restrict__ wv, const float* __restrict__ wm,
    const float* __restrict__ w1, const float* __restrict__ w2,
    unsigned short* __restrict__ qkvT, unsigned short* __restrict__ aoT,
    unsigned short* __restrict__ gaT, unsigned short* __restrict__ mT,
    unsigned short* __restrict__ f1T, unsigned short* __restrict__ f2T) {
    __shared__ float tile[32][33];
    int id = blockIdx.x;
    const float* src;
    unsigned short* dst;
    int K, N;
    if (id < 432)       {            src = wqkv; dst = qkvT;            K = 384; N = 1152; }
    else if (id < 576)  { id -= 432; src = wao;  dst = aoT;             K = 384; N = 384; }
    else if (id < 720)  { id -= 576; src = wq;   dst = gaT;             K = 384; N = 384; }
    else if (id < 864)  { id -= 720; src = wk;   dst = gaT + 384 * 384; K = 384; N = 384; }
    else if (id < 1008) { id -= 864; src = wv;   dst = gaT + 768 * 384; K = 384; N = 384; }
    else if (id < 1296) { id -= 1008; src = wm;  dst = mT;              K = 768; N = 384; }
    else if (id < 1584) { id -= 1296; src = w1;  dst = f1T;             K = 384; N = 768; }
    else                { id -= 1584; src = w2;  dst = f2T;             K = 768; N = 384; }
    int ntiles = N >> 5;
    int nt = id % ntiles, kt = id / ntiles;
    int tx = threadIdx.x, ty = threadIdx.y;
#pragma unroll
    for (int i = 0; i < 32; i += 8)
        tile[ty + i][tx] = src[(size_t)(kt * 32 + ty + i) * N + nt * 32 + tx];
    __syncthreads();
#pragma unroll
    for (int i = 0; i < 32; i += 8)
        dst[(size_t)(nt * 32 + ty + i) * K + kt * 32 + tx] = f2bf(tile[tx][ty + i]);
}

// features fp32 [B, D, N] -> F bf16 [B, N, D]
__global__ __launch_bounds__(256) void k_transpose_in(const float* __restrict__ feat,
                                                      unsigned short* __restrict__ f) {
    __shared__ float tile[32][33];
    int b = blockIdx.z;
    int n0 = blockIdx.x * 32, d0 = blockIdx.y * 32;
    int tx = threadIdx.x, ty = threadIdx.y;
#pragma unroll
    for (int i = 0; i < 32; i += 8)
        tile[ty + i][tx] = feat[((size_t)b * D_MODEL + d0 + ty + i) * NPTS + n0 + tx];
    __syncthreads();
#pragma unroll
    for (int i = 0; i < 32; i += 8)
        f[((size_t)b * NPTS + n0 + ty + i) * D_MODEL + d0 + tx] = f2bf(tile[tx][ty + i]);
}

// FFIN bf16 [B, N, D] -> out fp32 [B, D, N]
__global__ __launch_bounds__(256) void k_transpose_out(const unsigned short* __restrict__ f,
                                                       float* __restrict__ out) {
    __shared__ float tile[32][33];
    int b = blockIdx.z;
    int d0 = blockIdx.x * 32, n0 = blockIdx.y * 32;
    int tx = threadIdx.x, ty = threadIdx.y;
#pragma unroll
    for (int i = 0; i < 32; i += 8)
        tile[ty + i][tx] = bf2f(f[((size_t)b * NPTS + n0 + ty + i) * D_MODEL + d0 + tx]);
    __syncthreads();
#pragma unroll
    for (int i = 0; i < 32; i += 8)
        out[((size_t)b * D_MODEL + d0 + ty + i) * NPTS + n0 + tx] = tile[tx][ty + i];
}

// V slice of QKV [M,1152] (cols 768..1152) -> VT [B,H,64,NPTS]
__global__ __launch_bounds__(256) void k_vt(const unsigned short* __restrict__ qkv,
                                            unsigned short* __restrict__ vt) {
    __shared__ unsigned short tile[32][33];
    int b = blockIdx.z;
    int h = blockIdx.y >> 1, d0 = (blockIdx.y & 1) * 32;
    int n0 = blockIdx.x * 32;
    int tx = threadIdx.x, ty = threadIdx.y;
#pragma unroll
    for (int i = 0; i < 32; i += 8)
        tile[ty + i][tx] =
            qkv[((size_t)b * NPTS + n0 + ty + i) * 1152 + 768 + h * 64 + d0 + tx];
    __syncthreads();
#pragma unroll
    for (int i = 0; i < 32; i += 8)
        vt[(((size_t)(b * NHEAD + h) * 64) + d0 + ty + i) * NPTS + n0 + tx] = tile[tx][ty + i];
}

// LayerNorm over D=384 (bf16 in/out, fp32 g/b), one block (128 thr) per row
__global__ __launch_bounds__(128) void k_layernorm(const unsigned short* __restrict__ x,
                                                   const float* __restrict__ g,
                                                   const float* __restrict__ bt,
                                                   unsigned short* __restrict__ y) {
    int row = blockIdx.x, t = threadIdx.x;
    const unsigned short* xr = x + (size_t)row * D_MODEL;
    float v0 = bf2f(xr[t]), v1 = bf2f(xr[t + 128]), v2 = bf2f(xr[t + 256]);
    float s = v0 + v1 + v2;
    float s2 = v0 * v0 + v1 * v1 + v2 * v2;
#pragma unroll
    for (int off = 32; off > 0; off >>= 1) {
        s += __shfl_xor(s, off, 64);
        s2 += __shfl_xor(s2, off, 64);
    }
    __shared__ float ps[2], ps2[2];
    if ((t & 63) == 0) { ps[t >> 6] = s; ps2[t >> 6] = s2; }
    __syncthreads();
    s = ps[0] + ps[1];
    s2 = ps2[0] + ps2[1];
    float mean = s * (1.0f / 384.0f);
    float var = s2 * (1.0f / 384.0f) - mean * mean;
    var = fmaxf(var, 0.0f);
    float inv = 1.0f / sqrtf(var + 1e-5f);
    unsigned short* yr = y + (size_t)row * D_MODEL;
    yr[t]       = f2bf((v0 - mean) * inv * g[t]       + bt[t]);
    yr[t + 128] = f2bf((v1 - mean) * inv * g[t + 128] + bt[t + 128]);
    yr[t + 256] = f2bf((v2 - mean) * inv * g[t + 256] + bt[t + 256]);
}

// KNN v3: one wave per query, exact two-pass u32 selection.
// Pass 1: per-lane top-8 of u32 ordered-d2 VALUES (no index) via unconditional
// 2-op min/max bubble network; keys cached in 32 VGPRs (full unroll).
// Merge: 8 rounds of 64-lane u32-min butterfly + first-lane pop -> T8 = exact
// 8th-smallest value (multiset). Pass 2: strict (key<T8, provably <=7) winners
// write via ballot-prefix positions; remaining slots = lowest-index key==T8.
// Output order is arbitrary (k_geom + reference are permutation-invariant in
// the neighbor set); the SET matches top_k exactly (same d2 formula, same
// index tie-break).
__global__ __launch_bounds__(256) void k_knn(const float* __restrict__ coords,
                                             int* __restrict__ idx) {
    __shared__ float4 cpts[NPTS];
    int b = blockIdx.x >> 9;             // 512 blocks per batch
    int q0 = (blockIdx.x & 511) * 4;     // 4 queries (waves) per block
    const float* cb = coords + (size_t)b * 3 * NPTS;
    int tid = threadIdx.x;
#pragma unroll
    for (int i = 0; i < 8; i++) {
        int m = tid + i * 256;
        float x = cb[m], y = cb[NPTS + m], z = cb[2 * NPTS + m];
        float sq = __fadd_rn(__fadd_rn(__fmul_rn(x, x), __fmul_rn(y, y)), __fmul_rn(z, z));
        cpts[m] = make_float4(x, y, z, sq);
    }
    __syncthreads();
    int wv = tid >> 6, lane = tid & 63;
    int n = q0 + wv;
    float4 qp = cpts[n];
    float qx = qp.x, qy = qp.y, qz = qp.z, sqn = qp.w;
    unsigned keys[32];
    unsigned h[8];
#pragma unroll
    for (int k = 0; k < 8; k++) h[k] = 0xFFFFFFFFu;
#pragma unroll
    for (int j = 0; j < 32; j++) {
        float4 cp = cpts[j * 64 + lane];
        float dot = __fadd_rn(__fadd_rn(__fmul_rn(qx, cp.x), __fmul_rn(qy, cp.y)),
                              __fmul_rn(qz, cp.z));
        float d2 = __fsub_rn(__fadd_rn(sqn, cp.w), __fmul_rn(2.0f, dot));
        unsigned u = __float_as_uint(d2);
        u ^= (unsigned)(((int)u >> 31)) | 0x80000000u;  // order-preserving map
        keys[j] = u;
        unsigned cur = u;  // unconditional sorted-insert (no-op if u >= h[7])
#pragma unroll
        for (int t2 = 0; t2 < 8; t2++) {
            unsigned lo = h[t2] < cur ? h[t2] : cur;
            cur = h[t2] < cur ? cur : h[t2];
            h[t2] = lo;
        }
    }
    // Merge: serial-extract 8 smallest values of the union -> T8
    unsigned curh = h[0];
    unsigned T8 = 0;
#pragma unroll
    for (int r = 0; r < 8; r++) {
        unsigned w = curh;
#pragma unroll
        for (int off = 1; off < 64; off <<= 1) {
            unsigned o = __shfl_xor(w, off, 64);
            w = o < w ? o : w;
        }
        T8 = w;
        if (r < 7) {
            unsigned long long mask = __ballot(curh == w);
            if (curh == w && (mask & ((1ull << lane) - 1ull)) == 0) {
#pragma unroll
                for (int t2 = 0; t2 < 7; t2++) h[t2] = h[t2 + 1];
                h[7] = 0xFFFFFFFFu;
                curh = h[0];
            }
        }
    }
    // Pass 2: emit strict winners; track min eq index
    int* outr = idx + ((size_t)b * NPTS + n) * 8;
    int cnt = 0;
    unsigned meq = 0xFFFFFFFFu;
#pragma unroll
    for (int j = 0; j < 32; j++) {
        unsigned m = (unsigned)(j * 64 + lane);
        bool strict = keys[j] < T8;
        unsigned long long msk = __ballot(strict);
        if (strict) {
            int pos = cnt + (int)__popcll(msk & ((1ull << lane) - 1ull));
            outr[pos] = (int)m;
        }
        cnt += (int)__popcll(msk);
        if (keys[j] == T8 && m < meq) meq = m;
    }
    // Fill remaining slots with lowest-index key==T8 candidates
    while (cnt < 8) {
        unsigned w = meq;
#pragma unroll
        for (int off = 1; off < 64; off <<= 1) {
            unsigned o = __shfl_xor(w, off, 64);
            w = o < w ? o : w;
        }
        bool winner = (meq == w);
        if (winner) outr[cnt] = (int)w;
        cnt++;
        if (cnt >= 8) break;
        if (winner) {  // rare: advance to next eq index > w
            meq = 0xFFFFFFFFu;
#pragma unroll
            for (int j = 0; j < 32; j++) {
                unsigned m = (unsigned)(j * 64 + lane);
                if (keys[j] == T8 && m > w && m < meq) meq = m;
            }
        }
    }
}

// MFMA GEMM v5: 128x128 tile, BK=64. BOTH operands staged to LDS via async
// global_load_lds (16B, zero staging VALU), layout = two 128x32 chunks per
// operand (pitch 64B, proven v3 bank pattern). Operand-swapped MFMA
// (acc = W_frag x A_frag = C^T layout) so the epilogue's 4 acc regs per lane
// are contiguous columns -> ushort4 stores, uint2 res loads, float4 bias.
// A bf16 [M,K] (lda), WT bf16 [N,K], bias fp32, res/C bf16 (ldc).
__global__ __launch_bounds__(256) void k_gemm(const unsigned short* __restrict__ A, int lda,
                                              const unsigned short* __restrict__ WT,
                                              const float* __restrict__ bias,
                                              const unsigned short* __restrict__ res,
                                              unsigned short* __restrict__ C, int ldc,
                                              int K, int act) {
    __shared__ unsigned short Alds[2 * 128 * 32];  // 16 KB: [kc][row][32]
    __shared__ unsigned short Wlds[2 * 128 * 32];  // 16 KB: [kc][nrow][32]
    int tid = threadIdx.x;
    int wv = tid >> 6, lane = tid & 63;
    int l15 = lane & 15, quad = lane >> 4;
    int row0 = blockIdx.y * 128, col0 = blockIdx.x * 128;
    int wm = wv >> 1, wn = wv & 1;
    int wbase = tid & 192;  // wv*64
    floatx4 acc[4][4];
#pragma unroll
    for (int i = 0; i < 4; i++)
#pragma unroll
        for (int j = 0; j < 4; j++) acc[i][j] = (floatx4){0.f, 0.f, 0.f, 0.f};
    for (int k0 = 0; k0 < K; k0 += 64) {
#pragma unroll
        for (int i = 0; i < 4; i++) {
            int idx = i * 256 + tid;
            int kc = idx >> 9, row = (idx >> 2) & 127, ko = idx & 3;
            unsigned short* ldst = Alds + (size_t)(i * 256 + wbase) * 8;  // idx*16B, wave-uniform
            gload_lds16(A + (size_t)(row0 + row) * lda + k0 + kc * 32 + ko * 8, ldst);
            unsigned short* ldstw = Wlds + (size_t)(i * 256 + wbase) * 8;
            gload_lds16(WT + (size_t)(col0 + row) * K + k0 + kc * 32 + ko * 8, ldstw);
        }
        __syncthreads();  // drains global_load_lds
#pragma unroll
        for (int kc = 0; kc < 2; kc++) {
            short8 af[4], bf[4];
#pragma unroll
            for (int i = 0; i < 4; i++)
                af[i] = *(const short8*)&Alds[kc * 4096 + (wm * 64 + i * 16 + l15) * 32 + quad * 8];
#pragma unroll
            for (int j = 0; j < 4; j++)
                bf[j] = *(const short8*)&Wlds[kc * 4096 + (wn * 64 + j * 16 + l15) * 32 + quad * 8];
#pragma unroll
            for (int i = 0; i < 4; i++)
#pragma unroll
                for (int j = 0; j < 4; j++)
                    acc[i][j] =
                        __builtin_amdgcn_mfma_f32_16x16x32_bf16(bf[j], af[i], acc[i][j], 0, 0, 0);
        }
        __syncthreads();
    }
    // acc[i][j] is C^T-layout: D rows = n (quad*4+reg within j-tile), cols = m (l15)
#pragma unroll
    for (int i = 0; i < 4; i++) {
        int r = row0 + wm * 64 + i * 16 + l15;
#pragma unroll
        for (int j = 0; j < 4; j++) {
            int cb = col0 + wn * 64 + j * 16 + quad * 4;
            float4 bv = bias ? *(const float4*)(bias + cb) : make_float4(0.f, 0.f, 0.f, 0.f);
            float v0 = acc[i][j][0] + bv.x;
            float v1 = acc[i][j][1] + bv.y;
            float v2 = acc[i][j][2] + bv.z;
            float v3 = acc[i][j][3] + bv.w;
            if (act == 1) {
                v0 = gelu_tanh(v0); v1 = gelu_tanh(v1);
                v2 = gelu_tanh(v2); v3 = gelu_tanh(v3);
            }
            if (res) {
                uint2 rv = *(const uint2*)(res + (size_t)r * ldc + cb);
                const unsigned short* rs = (const unsigned short*)&rv;
                v0 += bf2f(rs[0]); v1 += bf2f(rs[1]);
                v2 += bf2f(rs[2]); v3 += bf2f(rs[3]);
            }
            ushort4 u;
            u.x = f2bf(v0); u.y = f2bf(v1); u.z = f2bf(v2); u.w = f2bf(v3);
            *(ushort4*)(C + (size_t)r * ldc + cb) = u;
        }
    }
}

// MFMA flash attention v5: no-max softmax (p = exp2(s), Q pre-scaled), VT
// pre-transposed in global. K/VT staged via global_load_lds (XOR-swizzled
// source, linear dest, swizzled frag reads), double-buffered, ONE barrier
// per tile. P packed in-register via v_cvt_pk_bf16_f32 into key-major
// Pt[key][16] (b64 writes), read back as PV B-frags via ds_read_b64_tr_b16.
// Row-sums l via ones-operand MFMA (D[i][j] = sum_k P[j][k]).
__global__ __launch_bounds__(256, 3) void k_attn(const unsigned short* __restrict__ qkv,
                                                 const unsigned short* __restrict__ vt,
                                                 unsigned short* __restrict__ attn) {
    __shared__ unsigned short Klds[2][64 * 64];  // 16 KB: [buf][key][dim] (swizzled slots)
    __shared__ unsigned short VTl[2][64 * 64];   // 16 KB: [buf][dim][key] (swizzled slots)
    __shared__ unsigned short Pt[4][2048];       // 16 KB: per wave, [qt][key][16 qrow]
    int b = blockIdx.z, h = blockIdx.y;
    int tid = threadIdx.x;
    int wv = tid >> 6, lane = tid & 63;
    int l15 = lane & 15, quad = lane >> 4;
    int qbase = blockIdx.x * 128 + wv * 32;
    const unsigned short* qkvb = qkv + (size_t)b * NPTS * 1152;
    const unsigned short* vtb = vt + (size_t)(b * NHEAD + h) * 64 * NPTS;
    const float SC = 0.18033688011112042f;  // 0.125 * log2(e)
    short8 qf[2][2];
#pragma unroll
    for (int qt = 0; qt < 2; qt++) {
        const unsigned short* qptr =
            qkvb + (size_t)(qbase + qt * 16 + l15) * 1152 + h * 64 + quad * 8;
        qf[qt][0] = *(const short8*)qptr;
        qf[qt][1] = *(const short8*)(qptr + 32);
#pragma unroll
        for (int g = 0; g < 2; g++) {  // fold softmax scale into Q once
            short8 v = qf[qt][g];
#pragma unroll
            for (int e = 0; e < 8; e++)
                v[e] = (short)f2bf(bf2f((unsigned short)v[e]) * SC);
            qf[qt][g] = v;
        }
    }
    short8 ones;
#pragma unroll
    for (int e = 0; e < 8; e++) ones[e] = (short)0x3F80;  // bf16 1.0
    int x7 = l15 & 7;
    int sk0 = ((quad ^ x7) << 4);        // swizzled byte slot, k-dims 0..31
    int sk1 = (((quad + 4) ^ x7) << 4);  // swizzled byte slot, k-dims 32..63
    unsigned pa = (unsigned)(size_t)(__attribute__((address_space(3))) unsigned short*)&Pt[wv][0] +
                  (unsigned)(quad * 256 + l15 * 2);
    int sdg = tid & 7;                   // staging: 16B slot within row
    floatx4 o[2][4];
#pragma unroll
    for (int qt = 0; qt < 2; qt++)
#pragma unroll
        for (int ct = 0; ct < 4; ct++) o[qt][ct] = (floatx4){0.f, 0.f, 0.f, 0.f};
    floatx4 l4[2];
    l4[0] = (floatx4){0.f, 0.f, 0.f, 0.f};
    l4[1] = (floatx4){0.f, 0.f, 0.f, 0.f};

    auto stage = [&](int c, int k0) {
#pragma unroll
        for (int i = 0; i < 2; i++) {
            int id = i * 256 + tid;
            int row = id >> 3;
            int sl = sdg ^ (row & 7);  // inverse-swizzled global slot
            gload_lds16(qkvb + (size_t)(k0 + row) * 1152 + 384 + h * 64 + sl * 8,
                        &Klds[c][(size_t)(i * 256 + (tid & 192)) * 8]);
            gload_lds16(vtb + (size_t)row * NPTS + k0 + sl * 8,
                        &VTl[c][(size_t)(i * 256 + (tid & 192)) * 8]);
        }
    };

    stage(0, 0);
    __syncthreads();
    for (int t = 0; t < 32; ++t) {
        int c = t & 1;
        if (t < 31) stage(c ^ 1, (t + 1) * 64);  // async DMA under compute
        const char* Kb = (const char*)&Klds[c][0];
        const char* Vb = (const char*)&VTl[c][0];
        short8 kf[4][2];
#pragma unroll
        for (int ct = 0; ct < 4; ct++) {
            kf[ct][0] = *(const short8*)(Kb + (ct * 16 + l15) * 128 + sk0);
            kf[ct][1] = *(const short8*)(Kb + (ct * 16 + l15) * 128 + sk1);
        }
#pragma unroll
        for (int qt = 0; qt < 2; qt++) {
            floatx4 s4[4];
#pragma unroll
            for (int ct = 0; ct < 4; ct++) {
                floatx4 z = (floatx4){0.f, 0.f, 0.f, 0.f};
                z = __builtin_amdgcn_mfma_f32_16x16x32_bf16(qf[qt][0], kf[ct][0], z, 0, 0, 0);
                z = __builtin_amdgcn_mfma_f32_16x16x32_bf16(qf[qt][1], kf[ct][1], z, 0, 0, 0);
                s4[ct] = z;
            }
#pragma unroll
            for (int ct = 0; ct < 4; ct++) {
                float p0 = __builtin_amdgcn_exp2f(s4[ct][0]);
                float p1 = __builtin_amdgcn_exp2f(s4[ct][1]);
                float p2 = __builtin_amdgcn_exp2f(s4[ct][2]);
                float p3 = __builtin_amdgcn_exp2f(s4[ct][3]);
                u32x2 pk;
                pk.x = cvtpk(p0, p1);
                pk.y = cvtpk(p2, p3);
                *(u32x2*)&Pt[wv][qt * 1024 + (ct * 16 + l15) * 16 + quad * 4] = pk;
            }
        }
        short8 vf[4][2];
#pragma unroll
        for (int ct = 0; ct < 4; ct++) {
            vf[ct][0] = *(const short8*)(Vb + (ct * 16 + l15) * 128 + sk0);
            vf[ct][1] = *(const short8*)(Vb + (ct * 16 + l15) * 128 + sk1);
        }
        asm volatile("s_waitcnt lgkmcnt(0)" ::: "memory");  // Pt writes done
        u32x2 q0g0l, q0g0h, q0g1l, q0g1h, q1g0l, q1g0h, q1g1l, q1g1h;
        TR16(q0g0l, pa, 0);
        TR16(q0g0h, pa, 128);
        TR16(q0g1l, pa, 1024);
        TR16(q0g1h, pa, 1152);
        TR16(q1g0l, pa, 2048);
        TR16(q1g0h, pa, 2176);
        TR16(q1g1l, pa, 3072);
        TR16(q1g1h, pa, 3200);
        asm volatile("s_waitcnt lgkmcnt(0)" ::: "memory");
        __builtin_amdgcn_sched_barrier(0);  // keep MFMAs below the tr reads
        short8 pf[2][2];
        pf[0][0] = __builtin_bit_cast(short8, (u32x4){q0g0l.x, q0g0l.y, q0g0h.x, q0g0h.y});
        pf[0][1] = __builtin_bit_cast(short8, (u32x4){q0g1l.x, q0g1l.y, q0g1h.x, q0g1h.y});
        pf[1][0] = __builtin_bit_cast(short8, (u32x4){q1g0l.x, q1g0l.y, q1g0h.x, q1g0h.y});
        pf[1][1] = __builtin_bit_cast(short8, (u32x4){q1g1l.x, q1g1l.y, q1g1h.x, q1g1h.y});
#pragma unroll
        for (int ct = 0; ct < 4; ct++) {
#pragma unroll
            for (int qt = 0; qt < 2; qt++) {
                o[qt][ct] = __builtin_amdgcn_mfma_f32_16x16x32_bf16(vf[ct][0], pf[qt][0], o[qt][ct], 0, 0, 0);
                o[qt][ct] = __builtin_amdgcn_mfma_f32_16x16x32_bf16(vf[ct][1], pf[qt][1], o[qt][ct], 0, 0, 0);
            }
        }
#pragma unroll
        for (int qt = 0; qt < 2; qt++) {
            l4[qt] = __builtin_amdgcn_mfma_f32_16x16x32_bf16(ones, pf[qt][0], l4[qt], 0, 0, 0);
            l4[qt] = __builtin_amdgcn_mfma_f32_16x16x32_bf16(ones, pf[qt][1], l4[qt], 0, 0, 0);
        }
        if (t < 31) __syncthreads();  // next tile's DMA + this tile's readers done
    }
#pragma unroll
    for (int qt = 0; qt < 2; qt++) {
        float linv = 1.0f / l4[qt][0];
#pragma unroll
        for (int ct = 0; ct < 4; ct++) {
            ushort4 u;
            u.x = f2bf(o[qt][ct][0] * linv);
            u.y = f2bf(o[qt][ct][1] * linv);
            u.z = f2bf(o[qt][ct][2] * linv);
            u.w = f2bf(o[qt][ct][3] * linv);
            *(ushort4*)(attn + ((size_t)b * NPTS + qbase + qt * 16 + l15) * 384 + h * 64 +
                        ct * 16 + quad * 4) = u;
        }
    }
}

// Graph attention: gq/nk/nv are column-slices of GAP [M,1152]. One wave per point.
// Writes geom into CAT[:, 384:768] (row stride 768).
__global__ __launch_bounds__(64) void k_geom(const unsigned short* __restrict__ gap,
                                             const int* __restrict__ idx,
                                             unsigned short* __restrict__ cat) {
    int r = blockIdx.x;
    int b = r >> 11;
    int t = threadIdx.x;
    int nb[8];
#pragma unroll
    for (int k = 0; k < 8; k++) nb[k] = idx[(size_t)r * 8 + k];
    const unsigned short* gqr = gap + (size_t)r * 1152;
    float qv[6];
#pragma unroll
    for (int j = 0; j < 6; j++) qv[j] = bf2f(gqr[t + 64 * j]);
    float s[8];
#pragma unroll
    for (int k = 0; k < 8; k++) {
        const unsigned short* nkr = gap + ((size_t)b * NPTS + nb[k]) * 1152 + 384;
        float acc = 0.0f;
#pragma unroll
        for (int j = 0; j < 6; j++) acc += qv[j] * bf2f(nkr[t + 64 * j]);
#pragma unroll
        for (int mm = 32; mm > 0; mm >>= 1) acc += __shfl_xor(acc, mm, 64);
        s[k] = acc * 0.05103103630798287f;  // 1/sqrt(384)
    }
    float mx = s[0];
#pragma unroll
    for (int k = 1; k < 8; k++) mx = fmaxf(mx, s[k]);
    float w[8];
    float sum = 0.0f;
#pragma unroll
    for (int k = 0; k < 8; k++) { w[k] = __expf(s[k] - mx); sum += w[k]; }
    float inv = 1.0f / sum;
    unsigned short* outr = cat + (size_t)r * 768 + 384;
#pragma unroll
    for (int j = 0; j < 6; j++) {
        int d = t + 64 * j;
        float acc = 0.0f;
#pragma unroll
        for (int k = 0; k < 8; k++)
            acc += w[k] * bf2f(gap[((size_t)b * NPTS + nb[k]) * 1152 + 768 + d]);
        outr[d] = f2bf(acc * inv);
    }
}

extern "C" void kernel_launch(void* const* d_in, const int* in_sizes, int n_in,
                              void* d_out, int out_size, void* d_ws, size_t ws_size,
                              hipStream_t stream) {
    (void)in_sizes; (void)n_in; (void)out_size; (void)ws_size;
    const float* coords     = (const float*)d_in[0];
    const float* features   = (const float*)d_in[1];
    const float* ln1_g      = (const float*)d_in[2];
    const float* ln1_b      = (const float*)d_in[3];
    const float* w_qkv      = (const float*)d_in[4];
    const float* w_attn_out = (const float*)d_in[5];
    const float* b_attn_out = (const float*)d_in[6];
    const float* ga_wq      = (const float*)d_in[7];
    const float* ga_wk      = (const float*)d_in[8];
    const float* ga_wv      = (const float*)d_in[9];
    const float* merge_w    = (const float*)d_in[10];
    const float* merge_b    = (const float*)d_in[11];
    const float* ln2_g      = (const float*)d_in[12];
    const float* ln2_b      = (const float*)d_in[13];
    const float* ff_w1      = (const float*)d_in[14];
    const float* ff_b1      = (const float*)d_in[15];
    const float* ff_w2      = (const float*)d_in[16];
    const float* ff_b2      = (const float*)d_in[17];

    // Workspace (bf16 units of SZ = 6,291,456 elems = 12 MiB). Overlay schedule:
    //   u0 F | u1 NF->HB | u2-4 QKV -> (CAT=u2-3, GAP=u4-6 after attn/AO) |
    //   u5 ATTN | u6 VT (dead before GAP gemm) | F2=u4 after geom | T1=u5-6 |
    //   FFIN=u2 | IDX + transposed weights after u7 (~4.3 MB). Peak ~100 MiB.
    unsigned short* W0 = (unsigned short*)d_ws;
    const size_t SZ = (size_t)BATCH * NPTS * D_MODEL;  // 6291456
    unsigned short* F    = W0 + 0 * SZ;
    unsigned short* NF   = W0 + 1 * SZ;
    unsigned short* QKV  = W0 + 2 * SZ;   // 3 units
    unsigned short* ATTN = W0 + 5 * SZ;
    unsigned short* VT   = W0 + 6 * SZ;   // [B,H,64,NPTS] = 1 unit
    unsigned short* CAT  = W0 + 2 * SZ;   // 2 units [M,768]
    unsigned short* GAP  = W0 + 4 * SZ;   // 3 units [M,1152]
    unsigned short* F2   = W0 + 4 * SZ;   // after GAP dead
    unsigned short* HB   = W0 + 1 * SZ;
    unsigned short* T1   = W0 + 5 * SZ;   // 2 units [M,768]
    unsigned short* FFIN = W0 + 2 * SZ;
    int*            IDX  = (int*)(W0 + 7 * SZ);
    unsigned short* WTS  = W0 + 7 * SZ + 262144;  // after IDX (512 KB)
    unsigned short* qkvT = WTS;                     // [1152,384]
    unsigned short* aoT  = qkvT + 442368;           // [384,384]
    unsigned short* gaT  = aoT + 147456;            // [1152,384]
    unsigned short* mT   = gaT + 442368;            // [384,768]
    unsigned short* f1T  = mT + 294912;             // [768,384]
    unsigned short* f2T  = f1T + 294912;            // [384,768]

    const int M = BATCH * NPTS;  // 16384

    k_wprep<<<1872, dim3(32, 8), 0, stream>>>(w_qkv, w_attn_out, ga_wq, ga_wk, ga_wv,
                                              merge_w, ff_w1, ff_w2,
                                              qkvT, aoT, gaT, mT, f1T, f2T);
    k_transpose_in<<<dim3(NPTS / 32, D_MODEL / 32, BATCH), dim3(32, 8), 0, stream>>>(features, F);
    k_layernorm<<<M, 128, 0, stream>>>(F, ln1_g, ln1_b, NF);
    k_knn<<<BATCH * (NPTS / 4), 256, 0, stream>>>(coords, IDX);
    // QKV = NF @ w_qkv
    k_gemm<<<dim3(9, M / 128), 256, 0, stream>>>(NF, 384, qkvT, nullptr, nullptr,
                                                 QKV, 1152, 384, 0);
    k_vt<<<dim3(NPTS / 32, 2 * NHEAD, BATCH), dim3(32, 8), 0, stream>>>(QKV, VT);
    k_attn<<<dim3(NPTS / 128, NHEAD, BATCH), 256, 0, stream>>>(QKV, VT, ATTN);
    // CAT[:, :384] = ATTN @ w_attn_out + b_attn_out
    k_gemm<<<dim3(3, M / 128), 256, 0, stream>>>(ATTN, 384, aoT, b_attn_out, nullptr,
                                                 CAT, 768, 384, 0);
    // GAP = NF @ [ga_wq | ga_wk | ga_wv]
    k_gemm<<<dim3(9, M / 128), 256, 0, stream>>>(NF, 384, gaT, nullptr, nullptr,
                                                 GAP, 1152, 384, 0);
    k_geom<<<M, 64, 0, stream>>>(GAP, IDX, CAT);
    // F2 = CAT @ merge_w + merge_b + F
    k_gemm<<<dim3(3, M / 128), 256, 0, stream>>>(CAT, 768, mT, merge_b, F,
                                                 F2, 384, 768, 0);
    k_layernorm<<<M, 128, 0, stream>>>(F2, ln2_g, ln2_b, HB);
    // T1 = gelu(HB @ ff_w1 + ff_b1)
    k_gemm<<<dim3(6, M / 128), 256, 0, stream>>>(HB, 384, f1T, ff_b1, nullptr,
                                                 T1, 768, 384, 1);
    // FFIN = F2 + T1 @ ff_w2 + ff_b2
    k_gemm<<<dim3(3, M / 128), 256, 0, stream>>>(T1, 768, f2T, ff_b2, F2,
                                                 FFIN, 384, 768, 0);
    k_transpose_out<<<dim3(D_MODEL / 32, NPTS / 32, BATCH), dim3(32, 8), 0, stream>>>(
        FFIN, (float*)d_out);
}

// Round 6
// 437.707 us; speedup vs baseline: 1.2602x; 1.0224x over previous
//
#include <hip/hip_runtime.h>
#include <hip/hip_bf16.h>
#include <cstdint>

#define D_MODEL 384
#define NHEAD 6
#define DHEAD 64
#define NPTS 2048
#define BATCH 8

typedef __attribute__((ext_vector_type(8))) short short8;
typedef __attribute__((ext_vector_type(4))) short short4v;
typedef __attribute__((ext_vector_type(4))) float floatx4;
typedef __attribute__((ext_vector_type(2))) unsigned int u32x2;

__device__ __forceinline__ float bf2f(unsigned short u) {
    return __uint_as_float(((unsigned int)u) << 16);
}

// round-to-nearest-even f32 -> bf16 (finite inputs only)
__device__ __forceinline__ unsigned short f2bf(float f) {
    unsigned int u = __float_as_uint(f);
    unsigned int r = (u + 0x7FFFu + ((u >> 16) & 1u)) >> 16;
    return (unsigned short)r;
}

// v_cvt_pk_bf16_f32: pack two f32 -> {bf16(lo), bf16(hi)} in one u32 (RNE)
__device__ __forceinline__ unsigned cvtpk(float lo, float hi) {
    unsigned r;
    asm("v_cvt_pk_bf16_f32 %0, %1, %2" : "=v"(r) : "v"(lo), "v"(hi));
    return r;
}

// 16x16x16 bf16 MFMA (A,B = 4 bf16/lane). Builtin if present, else exact
// gfx950 mnemonic per cdna4_isa.md §10.
__device__ __forceinline__ floatx4 mfma16(short4v a, short4v b, floatx4 c) {
#if __has_builtin(__builtin_amdgcn_mfma_f32_16x16x16bf16_1k)
    return __builtin_amdgcn_mfma_f32_16x16x16bf16_1k(a, b, c, 0, 0, 0);
#else
    floatx4 d;
    asm("v_mfma_f32_16x16x16_bf16 %0, %1, %2, %3" : "=v"(d) : "v"(a), "v"(b), "v"(c));
    return d;
#endif
}

__device__ __forceinline__ float gelu_tanh(float x) {
    float x3 = x * x * x;
    return 0.5f * x * (1.0f + tanhf(0.7978845608028654f * (x + 0.044715f * x3)));
}

// async 16B global -> LDS (wave-uniform LDS base + lane*16)
__device__ __forceinline__ void gload_lds16(const unsigned short* g, unsigned short* l) {
    __builtin_amdgcn_global_load_lds(
        (const __attribute__((address_space(1))) unsigned int*)g,
        (__attribute__((address_space(3))) unsigned int*)l, 16, 0, 0);
}

// Weight prep: fp32 [K,N] -> bf16 [N,K] (transposed), all 8 weights in one dispatch.
__global__ __launch_bounds__(256) void k_wprep(
    const float* __restrict__ wqkv, const float* __restrict__ wao,
    const float* __restrict__ wq, const float* __restrict__ wk,
    const float* __restrict__ wv, const float* __restrict__ wm,
    const float* __restrict__ w1, const float* __restrict__ w2,
    unsigned short* __restrict__ qkvT, unsigned short* __restrict__ aoT,
    unsigned short* __restrict__ gaT, unsigned short* __restrict__ mT,
    unsigned short* __restrict__ f1T, unsigned short* __restrict__ f2T) {
    __shared__ float tile[32][33];
    int id = blockIdx.x;
    const float* src;
    unsigned short* dst;
    int K, N;
    if (id < 432)       {            src = wqkv; dst = qkvT;            K = 384; N = 1152; }
    else if (id < 576)  { id -= 432; src = wao;  dst = aoT;             K = 384; N = 384; }
    else if (id < 720)  { id -= 576; src = wq;   dst = gaT;             K = 384; N = 384; }
    else if (id < 864)  { id -= 720; src = wk;   dst = gaT + 384 * 384; K = 384; N = 384; }
    else if (id < 1008) { id -= 864; src = wv;   dst = gaT + 768 * 384; K = 384; N = 384; }
    else if (id < 1296) { id -= 1008; src = wm;  dst = mT;              K = 768; N = 384; }
    else if (id < 1584) { id -= 1296; src = w1;  dst = f1T;             K = 384; N = 768; }
    else                { id -= 1584; src = w2;  dst = f2T;             K = 768; N = 384; }
    int ntiles = N >> 5;
    int nt = id % ntiles, kt = id / ntiles;
    int tx = threadIdx.x, ty = threadIdx.y;
#pragma unroll
    for (int i = 0; i < 32; i += 8)
        tile[ty + i][tx] = src[(size_t)(kt * 32 + ty + i) * N + nt * 32 + tx];
    __syncthreads();
#pragma unroll
    for (int i = 0; i < 32; i += 8)
        dst[(size_t)(nt * 32 + ty + i) * K + kt * 32 + tx] = f2bf(tile[tx][ty + i]);
}

// features fp32 [B, D, N] -> F bf16 [B, N, D]
__global__ __launch_bounds__(256) void k_transpose_in(const float* __restrict__ feat,
                                                      unsigned short* __restrict__ f) {
    __shared__ float tile[32][33];
    int b = blockIdx.z;
    int n0 = blockIdx.x * 32, d0 = blockIdx.y * 32;
    int tx = threadIdx.x, ty = threadIdx.y;
#pragma unroll
    for (int i = 0; i < 32; i += 8)
        tile[ty + i][tx] = feat[((size_t)b * D_MODEL + d0 + ty + i) * NPTS + n0 + tx];
    __syncthreads();
#pragma unroll
    for (int i = 0; i < 32; i += 8)
        f[((size_t)b * NPTS + n0 + ty + i) * D_MODEL + d0 + tx] = f2bf(tile[tx][ty + i]);
}

// FFIN bf16 [B, N, D] -> out fp32 [B, D, N]
__global__ __launch_bounds__(256) void k_transpose_out(const unsigned short* __restrict__ f,
                                                       float* __restrict__ out) {
    __shared__ float tile[32][33];
    int b = blockIdx.z;
    int d0 = blockIdx.x * 32, n0 = blockIdx.y * 32;
    int tx = threadIdx.x, ty = threadIdx.y;
#pragma unroll
    for (int i = 0; i < 32; i += 8)
        tile[ty + i][tx] = bf2f(f[((size_t)b * NPTS + n0 + ty + i) * D_MODEL + d0 + tx]);
    __syncthreads();
#pragma unroll
    for (int i = 0; i < 32; i += 8)
        out[((size_t)b * D_MODEL + d0 + ty + i) * NPTS + n0 + tx] = tile[tx][ty + i];
}

// V slice of QKV [M,1152] (cols 768..1152) -> VT [B,H,64,NPTS]
__global__ __launch_bounds__(256) void k_vt(const unsigned short* __restrict__ qkv,
                                            unsigned short* __restrict__ vt) {
    __shared__ unsigned short tile[32][33];
    int b = blockIdx.z;
    int h = blockIdx.y >> 1, d0 = (blockIdx.y & 1) * 32;
    int n0 = blockIdx.x * 32;
    int tx = threadIdx.x, ty = threadIdx.y;
#pragma unroll
    for (int i = 0; i < 32; i += 8)
        tile[ty + i][tx] =
            qkv[((size_t)b * NPTS + n0 + ty + i) * 1152 + 768 + h * 64 + d0 + tx];
    __syncthreads();
#pragma unroll
    for (int i = 0; i < 32; i += 8)
        vt[(((size_t)(b * NHEAD + h) * 64) + d0 + ty + i) * NPTS + n0 + tx] = tile[tx][ty + i];
}

// LayerNorm over D=384 (bf16 in/out, fp32 g/b), one block (128 thr) per row
__global__ __launch_bounds__(128) void k_layernorm(const unsigned short* __restrict__ x,
                                                   const float* __restrict__ g,
                                                   const float* __restrict__ bt,
                                                   unsigned short* __restrict__ y) {
    int row = blockIdx.x, t = threadIdx.x;
    const unsigned short* xr = x + (size_t)row * D_MODEL;
    float v0 = bf2f(xr[t]), v1 = bf2f(xr[t + 128]), v2 = bf2f(xr[t + 256]);
    float s = v0 + v1 + v2;
    float s2 = v0 * v0 + v1 * v1 + v2 * v2;
#pragma unroll
    for (int off = 32; off > 0; off >>= 1) {
        s += __shfl_xor(s, off, 64);
        s2 += __shfl_xor(s2, off, 64);
    }
    __shared__ float ps[2], ps2[2];
    if ((t & 63) == 0) { ps[t >> 6] = s; ps2[t >> 6] = s2; }
    __syncthreads();
    s = ps[0] + ps[1];
    s2 = ps2[0] + ps2[1];
    float mean = s * (1.0f / 384.0f);
    float var = s2 * (1.0f / 384.0f) - mean * mean;
    var = fmaxf(var, 0.0f);
    float inv = 1.0f / sqrtf(var + 1e-5f);
    unsigned short* yr = y + (size_t)row * D_MODEL;
    yr[t]       = f2bf((v0 - mean) * inv * g[t]       + bt[t]);
    yr[t + 128] = f2bf((v1 - mean) * inv * g[t + 128] + bt[t + 128]);
    yr[t + 256] = f2bf((v2 - mean) * inv * g[t + 256] + bt[t + 256]);
}

// KNN v3: one wave per query, exact two-pass u32 selection.
__global__ __launch_bounds__(256) void k_knn(const float* __restrict__ coords,
                                             int* __restrict__ idx) {
    __shared__ float4 cpts[NPTS];
    int b = blockIdx.x >> 9;             // 512 blocks per batch
    int q0 = (blockIdx.x & 511) * 4;     // 4 queries (waves) per block
    const float* cb = coords + (size_t)b * 3 * NPTS;
    int tid = threadIdx.x;
#pragma unroll
    for (int i = 0; i < 8; i++) {
        int m = tid + i * 256;
        float x = cb[m], y = cb[NPTS + m], z = cb[2 * NPTS + m];
        float sq = __fadd_rn(__fadd_rn(__fmul_rn(x, x), __fmul_rn(y, y)), __fmul_rn(z, z));
        cpts[m] = make_float4(x, y, z, sq);
    }
    __syncthreads();
    int wv = tid >> 6, lane = tid & 63;
    int n = q0 + wv;
    float4 qp = cpts[n];
    float qx = qp.x, qy = qp.y, qz = qp.z, sqn = qp.w;
    unsigned keys[32];
    unsigned h[8];
#pragma unroll
    for (int k = 0; k < 8; k++) h[k] = 0xFFFFFFFFu;
#pragma unroll
    for (int j = 0; j < 32; j++) {
        float4 cp = cpts[j * 64 + lane];
        float dot = __fadd_rn(__fadd_rn(__fmul_rn(qx, cp.x), __fmul_rn(qy, cp.y)),
                              __fmul_rn(qz, cp.z));
        float d2 = __fsub_rn(__fadd_rn(sqn, cp.w), __fmul_rn(2.0f, dot));
        unsigned u = __float_as_uint(d2);
        u ^= (unsigned)(((int)u >> 31)) | 0x80000000u;  // order-preserving map
        keys[j] = u;
        unsigned cur = u;  // unconditional sorted-insert (no-op if u >= h[7])
#pragma unroll
        for (int t2 = 0; t2 < 8; t2++) {
            unsigned lo = h[t2] < cur ? h[t2] : cur;
            cur = h[t2] < cur ? cur : h[t2];
            h[t2] = lo;
        }
    }
    // Merge: serial-extract 8 smallest values of the union -> T8
    unsigned curh = h[0];
    unsigned T8 = 0;
#pragma unroll
    for (int r = 0; r < 8; r++) {
        unsigned w = curh;
#pragma unroll
        for (int off = 1; off < 64; off <<= 1) {
            unsigned o = __shfl_xor(w, off, 64);
            w = o < w ? o : w;
        }
        T8 = w;
        if (r < 7) {
            unsigned long long mask = __ballot(curh == w);
            if (curh == w && (mask & ((1ull << lane) - 1ull)) == 0) {
#pragma unroll
                for (int t2 = 0; t2 < 7; t2++) h[t2] = h[t2 + 1];
                h[7] = 0xFFFFFFFFu;
                curh = h[0];
            }
        }
    }
    // Pass 2: emit strict winners; track min eq index
    int* outr = idx + ((size_t)b * NPTS + n) * 8;
    int cnt = 0;
    unsigned meq = 0xFFFFFFFFu;
#pragma unroll
    for (int j = 0; j < 32; j++) {
        unsigned m = (unsigned)(j * 64 + lane);
        bool strict = keys[j] < T8;
        unsigned long long msk = __ballot(strict);
        if (strict) {
            int pos = cnt + (int)__popcll(msk & ((1ull << lane) - 1ull));
            outr[pos] = (int)m;
        }
        cnt += (int)__popcll(msk);
        if (keys[j] == T8 && m < meq) meq = m;
    }
    // Fill remaining slots with lowest-index key==T8 candidates
    while (cnt < 8) {
        unsigned w = meq;
#pragma unroll
        for (int off = 1; off < 64; off <<= 1) {
            unsigned o = __shfl_xor(w, off, 64);
            w = o < w ? o : w;
        }
        bool winner = (meq == w);
        if (winner) outr[cnt] = (int)w;
        cnt++;
        if (cnt >= 8) break;
        if (winner) {  // rare: advance to next eq index > w
            meq = 0xFFFFFFFFu;
#pragma unroll
            for (int j = 0; j < 32; j++) {
                unsigned m = (unsigned)(j * 64 + lane);
                if (keys[j] == T8 && m > w && m < meq) meq = m;
            }
        }
    }
}

// MFMA GEMM v5: 128x128 tile, BK=64. BOTH operands staged to LDS via async
// global_load_lds (16B, zero staging VALU). Operand-swapped MFMA (C^T layout).
// A bf16 [M,K] (lda), WT bf16 [N,K], bias fp32, res/C bf16 (ldc).
__global__ __launch_bounds__(256) void k_gemm(const unsigned short* __restrict__ A, int lda,
                                              const unsigned short* __restrict__ WT,
                                              const float* __restrict__ bias,
                                              const unsigned short* __restrict__ res,
                                              unsigned short* __restrict__ C, int ldc,
                                              int K, int act) {
    __shared__ unsigned short Alds[2 * 128 * 32];  // 16 KB: [kc][row][32]
    __shared__ unsigned short Wlds[2 * 128 * 32];  // 16 KB: [kc][nrow][32]
    int tid = threadIdx.x;
    int wv = tid >> 6, lane = tid & 63;
    int l15 = lane & 15, quad = lane >> 4;
    int row0 = blockIdx.y * 128, col0 = blockIdx.x * 128;
    int wm = wv >> 1, wn = wv & 1;
    int wbase = tid & 192;  // wv*64
    floatx4 acc[4][4];
#pragma unroll
    for (int i = 0; i < 4; i++)
#pragma unroll
        for (int j = 0; j < 4; j++) acc[i][j] = (floatx4){0.f, 0.f, 0.f, 0.f};
    for (int k0 = 0; k0 < K; k0 += 64) {
#pragma unroll
        for (int i = 0; i < 4; i++) {
            int idx = i * 256 + tid;
            int kc = idx >> 9, row = (idx >> 2) & 127, ko = idx & 3;
            unsigned short* ldst = Alds + (size_t)(i * 256 + wbase) * 8;  // idx*16B, wave-uniform
            gload_lds16(A + (size_t)(row0 + row) * lda + k0 + kc * 32 + ko * 8, ldst);
            unsigned short* ldstw = Wlds + (size_t)(i * 256 + wbase) * 8;
            gload_lds16(WT + (size_t)(col0 + row) * K + k0 + kc * 32 + ko * 8, ldstw);
        }
        __syncthreads();  // drains global_load_lds
#pragma unroll
        for (int kc = 0; kc < 2; kc++) {
            short8 af[4], bf[4];
#pragma unroll
            for (int i = 0; i < 4; i++)
                af[i] = *(const short8*)&Alds[kc * 4096 + (wm * 64 + i * 16 + l15) * 32 + quad * 8];
#pragma unroll
            for (int j = 0; j < 4; j++)
                bf[j] = *(const short8*)&Wlds[kc * 4096 + (wn * 64 + j * 16 + l15) * 32 + quad * 8];
#pragma unroll
            for (int i = 0; i < 4; i++)
#pragma unroll
                for (int j = 0; j < 4; j++)
                    acc[i][j] =
                        __builtin_amdgcn_mfma_f32_16x16x32_bf16(bf[j], af[i], acc[i][j], 0, 0, 0);
        }
        __syncthreads();
    }
    // acc[i][j] is C^T-layout: D rows = n (quad*4+reg within j-tile), cols = m (l15)
#pragma unroll
    for (int i = 0; i < 4; i++) {
        int r = row0 + wm * 64 + i * 16 + l15;
#pragma unroll
        for (int j = 0; j < 4; j++) {
            int cb = col0 + wn * 64 + j * 16 + quad * 4;
            float4 bv = bias ? *(const float4*)(bias + cb) : make_float4(0.f, 0.f, 0.f, 0.f);
            float v0 = acc[i][j][0] + bv.x;
            float v1 = acc[i][j][1] + bv.y;
            float v2 = acc[i][j][2] + bv.z;
            float v3 = acc[i][j][3] + bv.w;
            if (act == 1) {
                v0 = gelu_tanh(v0); v1 = gelu_tanh(v1);
                v2 = gelu_tanh(v2); v3 = gelu_tanh(v3);
            }
            if (res) {
                uint2 rv = *(const uint2*)(res + (size_t)r * ldc + cb);
                const unsigned short* rs = (const unsigned short*)&rv;
                v0 += bf2f(rs[0]); v1 += bf2f(rs[1]);
                v2 += bf2f(rs[2]); v3 += bf2f(rs[3]);
            }
            ushort4 u;
            u.x = f2bf(v0); u.y = f2bf(v1); u.z = f2bf(v2); u.w = f2bf(v3);
            *(ushort4*)(C + (size_t)r * ldc + cb) = u;
        }
    }
}

// MFMA flash attention v6: swapped QK^T (z = mfma(K,Q)) puts P[key][q] rows in
// registers; cvt_pk pairs form the 16x16x16 PV B-fragment DIRECTLY -> the whole
// Pt LDS round-trip (writes + tr-reads + 2 lgkm drains) is deleted. PV = 32
// mfma16 per tile; V frags via 16 ds_read_b64. Row-sum l via ones-MFMA (K=16).
// K/VT staged via global_load_lds (XOR-swizzled source, linear dest), double-
// buffered, one barrier per tile. LDS 32 KB (was 48).
__global__ __launch_bounds__(256, 3) void k_attn(const unsigned short* __restrict__ qkv,
                                                 const unsigned short* __restrict__ vt,
                                                 unsigned short* __restrict__ attn) {
    __shared__ unsigned short Klds[2][64 * 64];  // 16 KB: [buf][key][dim] (swizzled slots)
    __shared__ unsigned short VTl[2][64 * 64];   // 16 KB: [buf][dim][key] (swizzled slots)
    int b = blockIdx.z, h = blockIdx.y;
    int tid = threadIdx.x;
    int wv = tid >> 6, lane = tid & 63;
    int l15 = lane & 15, quad = lane >> 4;
    int qbase = blockIdx.x * 128 + wv * 32;
    const unsigned short* qkvb = qkv + (size_t)b * NPTS * 1152;
    const unsigned short* vtb = vt + (size_t)(b * NHEAD + h) * 64 * NPTS;
    const float SC = 0.18033688011112042f;  // 0.125 * log2(e)
    short8 qf[2][2];
#pragma unroll
    for (int qt = 0; qt < 2; qt++) {
        const unsigned short* qptr =
            qkvb + (size_t)(qbase + qt * 16 + l15) * 1152 + h * 64 + quad * 8;
        qf[qt][0] = *(const short8*)qptr;
        qf[qt][1] = *(const short8*)(qptr + 32);
#pragma unroll
        for (int g = 0; g < 2; g++) {  // fold softmax scale into Q once
            short8 v = qf[qt][g];
#pragma unroll
            for (int e = 0; e < 8; e++)
                v[e] = (short)f2bf(bf2f((unsigned short)v[e]) * SC);
            qf[qt][g] = v;
        }
    }
    short4v ones4;
#pragma unroll
    for (int e = 0; e < 4; e++) ones4[e] = (short)0x3F80;  // bf16 1.0
    int x7 = l15 & 7;
    int sk0 = ((quad ^ x7) << 4);        // K read: swizzled slot, dims 0..31
    int sk1 = (((quad + 4) ^ x7) << 4);  // K read: swizzled slot, dims 32..63
    int vslot[4];                        // V read: per-kt swizzled slot
#pragma unroll
    for (int kt = 0; kt < 4; kt++) vslot[kt] = (((kt * 2 + (quad >> 1)) ^ x7) << 4);
    int vsub = (quad & 1) * 8;           // 8B half within the 16B slot
    int sdg = tid & 7;                   // staging: 16B slot within row
    floatx4 o[2][4];
#pragma unroll
    for (int qt = 0; qt < 2; qt++)
#pragma unroll
        for (int ct = 0; ct < 4; ct++) o[qt][ct] = (floatx4){0.f, 0.f, 0.f, 0.f};
    floatx4 l4[2];
    l4[0] = (floatx4){0.f, 0.f, 0.f, 0.f};
    l4[1] = (floatx4){0.f, 0.f, 0.f, 0.f};

    auto stage = [&](int c, int k0) {
#pragma unroll
        for (int i = 0; i < 2; i++) {
            int id = i * 256 + tid;
            int row = id >> 3;
            int sl = sdg ^ (row & 7);  // inverse-swizzled global slot
            gload_lds16(qkvb + (size_t)(k0 + row) * 1152 + 384 + h * 64 + sl * 8,
                        &Klds[c][(size_t)(i * 256 + (tid & 192)) * 8]);
            gload_lds16(vtb + (size_t)row * NPTS + k0 + sl * 8,
                        &VTl[c][(size_t)(i * 256 + (tid & 192)) * 8]);
        }
    };

    stage(0, 0);
    __syncthreads();
    for (int t = 0; t < 32; ++t) {
        int c = t & 1;
        if (t < 31) stage(c ^ 1, (t + 1) * 64);  // async DMA under compute
        const char* Kb = (const char*)&Klds[c][0];
        const char* Vb = (const char*)&VTl[c][0];
        short8 kf[4][2];
#pragma unroll
        for (int ct = 0; ct < 4; ct++) {
            kf[ct][0] = *(const short8*)(Kb + (ct * 16 + l15) * 128 + sk0);
            kf[ct][1] = *(const short8*)(Kb + (ct * 16 + l15) * 128 + sk1);
        }
        // QK^T swapped: lane holds P[key = ct*16 + quad*4 + r][q = l15]
        short4v pf16[2][4];
#pragma unroll
        for (int qt = 0; qt < 2; qt++) {
#pragma unroll
            for (int ct = 0; ct < 4; ct++) {
                floatx4 z = (floatx4){0.f, 0.f, 0.f, 0.f};
                z = __builtin_amdgcn_mfma_f32_16x16x32_bf16(kf[ct][0], qf[qt][0], z, 0, 0, 0);
                z = __builtin_amdgcn_mfma_f32_16x16x32_bf16(kf[ct][1], qf[qt][1], z, 0, 0, 0);
                float p0 = __builtin_amdgcn_exp2f(z[0]);
                float p1 = __builtin_amdgcn_exp2f(z[1]);
                float p2 = __builtin_amdgcn_exp2f(z[2]);
                float p3 = __builtin_amdgcn_exp2f(z[3]);
                u32x2 pk;
                pk.x = cvtpk(p0, p1);
                pk.y = cvtpk(p2, p3);
                pf16[qt][ct] = __builtin_bit_cast(short4v, pk);  // B-frag of mfma16
            }
        }
        // PV: o[dim-tile ctd] += V^T-frag(ctd,kt) x P-frag(kt), K=16 per step
        const char* vb0 = Vb + l15 * 128 + vsub;
#pragma unroll
        for (int ctd = 0; ctd < 4; ctd++) {
            short4v va[4];
#pragma unroll
            for (int kt = 0; kt < 4; kt++)
                va[kt] = *(const short4v*)(vb0 + ctd * 2048 + vslot[kt]);
#pragma unroll
            for (int kt = 0; kt < 4; kt++) {
#pragma unroll
                for (int qt = 0; qt < 2; qt++)
                    o[qt][ctd] = mfma16(va[kt], pf16[qt][kt], o[qt][ctd]);
            }
        }
#pragma unroll
        for (int qt = 0; qt < 2; qt++)
#pragma unroll
            for (int kt = 0; kt < 4; kt++) l4[qt] = mfma16(ones4, pf16[qt][kt], l4[qt]);
        if (t < 31) __syncthreads();  // next tile's DMA + this tile's readers done
    }
#pragma unroll
    for (int qt = 0; qt < 2; qt++) {
        float linv = 1.0f / l4[qt][0];
#pragma unroll
        for (int ct = 0; ct < 4; ct++) {
            ushort4 u;
            u.x = f2bf(o[qt][ct][0] * linv);
            u.y = f2bf(o[qt][ct][1] * linv);
            u.z = f2bf(o[qt][ct][2] * linv);
            u.w = f2bf(o[qt][ct][3] * linv);
            *(ushort4*)(attn + ((size_t)b * NPTS + qbase + qt * 16 + l15) * 384 + h * 64 +
                        ct * 16 + quad * 4) = u;
        }
    }
}

// Graph attention: gq/nk/nv are column-slices of GAP [M,1152]. One wave per point.
// Writes geom into CAT[:, 384:768] (row stride 768).
__global__ __launch_bounds__(64) void k_geom(const unsigned short* __restrict__ gap,
                                             const int* __restrict__ idx,
                                             unsigned short* __restrict__ cat) {
    int r = blockIdx.x;
    int b = r >> 11;
    int t = threadIdx.x;
    int nb[8];
#pragma unroll
    for (int k = 0; k < 8; k++) nb[k] = idx[(size_t)r * 8 + k];
    const unsigned short* gqr = gap + (size_t)r * 1152;
    float qv[6];
#pragma unroll
    for (int j = 0; j < 6; j++) qv[j] = bf2f(gqr[t + 64 * j]);
    float s[8];
#pragma unroll
    for (int k = 0; k < 8; k++) {
        const unsigned short* nkr = gap + ((size_t)b * NPTS + nb[k]) * 1152 + 384;
        float acc = 0.0f;
#pragma unroll
        for (int j = 0; j < 6; j++) acc += qv[j] * bf2f(nkr[t + 64 * j]);
#pragma unroll
        for (int mm = 32; mm > 0; mm >>= 1) acc += __shfl_xor(acc, mm, 64);
        s[k] = acc * 0.05103103630798287f;  // 1/sqrt(384)
    }
    float mx = s[0];
#pragma unroll
    for (int k = 1; k < 8; k++) mx = fmaxf(mx, s[k]);
    float w[8];
    float sum = 0.0f;
#pragma unroll
    for (int k = 0; k < 8; k++) { w[k] = __expf(s[k] - mx); sum += w[k]; }
    float inv = 1.0f / sum;
    unsigned short* outr = cat + (size_t)r * 768 + 384;
#pragma unroll
    for (int j = 0; j < 6; j++) {
        int d = t + 64 * j;
        float acc = 0.0f;
#pragma unroll
        for (int k = 0; k < 8; k++)
            acc += w[k] * bf2f(gap[((size_t)b * NPTS + nb[k]) * 1152 + 768 + d]);
        outr[d] = f2bf(acc * inv);
    }
}

extern "C" void kernel_launch(void* const* d_in, const int* in_sizes, int n_in,
                              void* d_out, int out_size, void* d_ws, size_t ws_size,
                              hipStream_t stream) {
    (void)in_sizes; (void)n_in; (void)out_size; (void)ws_size;
    const float* coords     = (const float*)d_in[0];
    const float* features   = (const float*)d_in[1];
    const float* ln1_g      = (const float*)d_in[2];
    const float* ln1_b      = (const float*)d_in[3];
    const float* w_qkv      = (const float*)d_in[4];
    const float* w_attn_out = (const float*)d_in[5];
    const float* b_attn_out = (const float*)d_in[6];
    const float* ga_wq      = (const float*)d_in[7];
    const float* ga_wk      = (const float*)d_in[8];
    const float* ga_wv      = (const float*)d_in[9];
    const float* merge_w    = (const float*)d_in[10];
    const float* merge_b    = (const float*)d_in[11];
    const float* ln2_g      = (const float*)d_in[12];
    const float* ln2_b      = (const float*)d_in[13];
    const float* ff_w1      = (const float*)d_in[14];
    const float* ff_b1      = (const float*)d_in[15];
    const float* ff_w2      = (const float*)d_in[16];
    const float* ff_b2      = (const float*)d_in[17];

    // Workspace (bf16 units of SZ = 6,291,456 elems = 12 MiB). Overlay schedule:
    //   u0 F | u1 NF->HB | u2-4 QKV -> (CAT=u2-3, GAP=u4-6 after attn/AO) |
    //   u5 ATTN | u6 VT (dead before GAP gemm) | F2=u4 after geom | T1=u5-6 |
    //   FFIN=u2 | IDX + transposed weights after u7 (~4.3 MB). Peak ~100 MiB.
    unsigned short* W0 = (unsigned short*)d_ws;
    const size_t SZ = (size_t)BATCH * NPTS * D_MODEL;  // 6291456
    unsigned short* F    = W0 + 0 * SZ;
    unsigned short* NF   = W0 + 1 * SZ;
    unsigned short* QKV  = W0 + 2 * SZ;   // 3 units
    unsigned short* ATTN = W0 + 5 * SZ;
    unsigned short* VT   = W0 + 6 * SZ;   // [B,H,64,NPTS] = 1 unit
    unsigned short* CAT  = W0 + 2 * SZ;   // 2 units [M,768]
    unsigned short* GAP  = W0 + 4 * SZ;   // 3 units [M,1152]
    unsigned short* F2   = W0 + 4 * SZ;   // after GAP dead
    unsigned short* HB   = W0 + 1 * SZ;
    unsigned short* T1   = W0 + 5 * SZ;   // 2 units [M,768]
    unsigned short* FFIN = W0 + 2 * SZ;
    int*            IDX  = (int*)(W0 + 7 * SZ);
    unsigned short* WTS  = W0 + 7 * SZ + 262144;  // after IDX (512 KB)
    unsigned short* qkvT = WTS;                     // [1152,384]
    unsigned short* aoT  = qkvT + 442368;           // [384,384]
    unsigned short* gaT  = aoT + 147456;            // [1152,384]
    unsigned short* mT   = gaT + 442368;            // [384,768]
    unsigned short* f1T  = mT + 294912;             // [768,384]
    unsigned short* f2T  = f1T + 294912;            // [384,768]

    const int M = BATCH * NPTS;  // 16384

    k_wprep<<<1872, dim3(32, 8), 0, stream>>>(w_qkv, w_attn_out, ga_wq, ga_wk, ga_wv,
                                              merge_w, ff_w1, ff_w2,
                                              qkvT, aoT, gaT, mT, f1T, f2T);
    k_transpose_in<<<dim3(NPTS / 32, D_MODEL / 32, BATCH), dim3(32, 8), 0, stream>>>(features, F);
    k_layernorm<<<M, 128, 0, stream>>>(F, ln1_g, ln1_b, NF);
    k_knn<<<BATCH * (NPTS / 4), 256, 0, stream>>>(coords, IDX);
    // QKV = NF @ w_qkv
    k_gemm<<<dim3(9, M / 128), 256, 0, stream>>>(NF, 384, qkvT, nullptr, nullptr,
                                                 QKV, 1152, 384, 0);
    k_vt<<<dim3(NPTS / 32, 2 * NHEAD, BATCH), dim3(32, 8), 0, stream>>>(QKV, VT);
    k_attn<<<dim3(NPTS / 128, NHEAD, BATCH), 256, 0, stream>>>(QKV, VT, ATTN);
    // CAT[:, :384] = ATTN @ w_attn_out + b_attn_out
    k_gemm<<<dim3(3, M / 128), 256, 0, stream>>>(ATTN, 384, aoT, b_attn_out, nullptr,
                                                 CAT, 768, 384, 0);
    // GAP = NF @ [ga_wq | ga_wk | ga_wv]
    k_gemm<<<dim3(9, M / 128), 256, 0, stream>>>(NF, 384, gaT, nullptr, nullptr,
                                                 GAP, 1152, 384, 0);
    k_geom<<<M, 64, 0, stream>>>(GAP, IDX, CAT);
    // F2 = CAT @ merge_w + merge_b + F
    k_gemm<<<dim3(3, M / 128), 256, 0, stream>>>(CAT, 768, mT, merge_b, F,
                                                 F2, 384, 768, 0);
    k_layernorm<<<M, 128, 0, stream>>>(F2, ln2_g, ln2_b, HB);
    // T1 = gelu(HB @ ff_w1 + ff_b1)
    k_gemm<<<dim3(6, M / 128), 256, 0, stream>>>(HB, 384, f1T, ff_b1, nullptr,
                                                 T1, 768, 384, 1);
    // FFIN = F2 + T1 @ ff_w2 + ff_b2
    k_gemm<<<dim3(3, M / 128), 256, 0, stream>>>(T1, 768, f2T, ff_b2, F2,
                                                 FFIN, 384, 768, 0);
    k_transpose_out<<<dim3(D_MODEL / 32, NPTS / 32, BATCH), dim3(32, 8), 0, stream>>>(
        FFIN, (float*)d_out);
}

// Round 7
// 416.615 us; speedup vs baseline: 1.3240x; 1.0506x over previous
//
#include <hip/hip_runtime.h>
#include <hip/hip_bf16.h>
#include <cstdint>

#define D_MODEL 384
#define NHEAD 6
#define DHEAD 64
#define NPTS 2048
#define BATCH 8

typedef __attribute__((ext_vector_type(8))) short short8;
typedef __attribute__((ext_vector_type(4))) short short4v;
typedef __attribute__((ext_vector_type(4))) float floatx4;
typedef __attribute__((ext_vector_type(2))) unsigned int u32x2;

__device__ __forceinline__ float bf2f(unsigned short u) {
    return __uint_as_float(((unsigned int)u) << 16);
}

// round-to-nearest-even f32 -> bf16 (finite inputs only)
__device__ __forceinline__ unsigned short f2bf(float f) {
    unsigned int u = __float_as_uint(f);
    unsigned int r = (u + 0x7FFFu + ((u >> 16) & 1u)) >> 16;
    return (unsigned short)r;
}

// v_cvt_pk_bf16_f32: pack two f32 -> {bf16(lo), bf16(hi)} in one u32 (RNE)
__device__ __forceinline__ unsigned cvtpk(float lo, float hi) {
    unsigned r;
    asm("v_cvt_pk_bf16_f32 %0, %1, %2" : "=v"(r) : "v"(lo), "v"(hi));
    return r;
}

// 16x16x16 bf16 MFMA (A,B = 4 bf16/lane). Builtin if present, else exact
// gfx950 mnemonic per cdna4_isa.md §10.
__device__ __forceinline__ floatx4 mfma16(short4v a, short4v b, floatx4 c) {
#if __has_builtin(__builtin_amdgcn_mfma_f32_16x16x16bf16_1k)
    return __builtin_amdgcn_mfma_f32_16x16x16bf16_1k(a, b, c, 0, 0, 0);
#else
    floatx4 d;
    asm("v_mfma_f32_16x16x16_bf16 %0, %1, %2, %3" : "=v"(d) : "v"(a), "v"(b), "v"(c));
    return d;
#endif
}

__device__ __forceinline__ float gelu_tanh(float x) {
    float x3 = x * x * x;
    return 0.5f * x * (1.0f + tanhf(0.7978845608028654f * (x + 0.044715f * x3)));
}

// async 16B global -> LDS (wave-uniform LDS base + lane*16)
__device__ __forceinline__ void gload_lds16(const unsigned short* g, unsigned short* l) {
    __builtin_amdgcn_global_load_lds(
        (const __attribute__((address_space(1))) unsigned int*)g,
        (__attribute__((address_space(3))) unsigned int*)l, 16, 0, 0);
}

// Weight prep: fp32 [K,N] -> bf16 [N,K] (transposed), all 8 weights in one dispatch.
__global__ __launch_bounds__(256) void k_wprep(
    const float* __restrict__ wqkv, const float* __restrict__ wao,
    const float* __restrict__ wq, const float* __restrict__ wk,
    const float* __restrict__ wv, const float* __restrict__ wm,
    const float* __restrict__ w1, const float* __restrict__ w2,
    unsigned short* __restrict__ qkvT, unsigned short* __restrict__ aoT,
    unsigned short* __restrict__ gaT, unsigned short* __restrict__ mT,
    unsigned short* __restrict__ f1T, unsigned short* __restrict__ f2T) {
    __shared__ float tile[32][33];
    int id = blockIdx.x;
    const float* src;
    unsigned short* dst;
    int K, N;
    if (id < 432)       {            src = wqkv; dst = qkvT;            K = 384; N = 1152; }
    else if (id < 576)  { id -= 432; src = wao;  dst = aoT;             K = 384; N = 384; }
    else if (id < 720)  { id -= 576; src = wq;   dst = gaT;             K = 384; N = 384; }
    else if (id < 864)  { id -= 720; src = wk;   dst = gaT + 384 * 384; K = 384; N = 384; }
    else if (id < 1008) { id -= 864; src = wv;   dst = gaT + 768 * 384; K = 384; N = 384; }
    else if (id < 1296) { id -= 1008; src = wm;  dst = mT;              K = 768; N = 384; }
    else if (id < 1584) { id -= 1296; src = w1;  dst = f1T;             K = 384; N = 768; }
    else                { id -= 1584; src = w2;  dst = f2T;             K = 768; N = 384; }
    int ntiles = N >> 5;
    int nt = id % ntiles, kt = id / ntiles;
    int tx = threadIdx.x, ty = threadIdx.y;
#pragma unroll
    for (int i = 0; i < 32; i += 8)
        tile[ty + i][tx] = src[(size_t)(kt * 32 + ty + i) * N + nt * 32 + tx];
    __syncthreads();
#pragma unroll
    for (int i = 0; i < 32; i += 8)
        dst[(size_t)(nt * 32 + ty + i) * K + kt * 32 + tx] = f2bf(tile[tx][ty + i]);
}

// features fp32 [B, D, N] -> F bf16 [B, N, D]
__global__ __launch_bounds__(256) void k_transpose_in(const float* __restrict__ feat,
                                                      unsigned short* __restrict__ f) {
    __shared__ float tile[32][33];
    int b = blockIdx.z;
    int n0 = blockIdx.x * 32, d0 = blockIdx.y * 32;
    int tx = threadIdx.x, ty = threadIdx.y;
#pragma unroll
    for (int i = 0; i < 32; i += 8)
        tile[ty + i][tx] = feat[((size_t)b * D_MODEL + d0 + ty + i) * NPTS + n0 + tx];
    __syncthreads();
#pragma unroll
    for (int i = 0; i < 32; i += 8)
        f[((size_t)b * NPTS + n0 + ty + i) * D_MODEL + d0 + tx] = f2bf(tile[tx][ty + i]);
}

// FFIN bf16 [B, N, D] -> out fp32 [B, D, N]
__global__ __launch_bounds__(256) void k_transpose_out(const unsigned short* __restrict__ f,
                                                       float* __restrict__ out) {
    __shared__ float tile[32][33];
    int b = blockIdx.z;
    int d0 = blockIdx.x * 32, n0 = blockIdx.y * 32;
    int tx = threadIdx.x, ty = threadIdx.y;
#pragma unroll
    for (int i = 0; i < 32; i += 8)
        tile[ty + i][tx] = bf2f(f[((size_t)b * NPTS + n0 + ty + i) * D_MODEL + d0 + tx]);
    __syncthreads();
#pragma unroll
    for (int i = 0; i < 32; i += 8)
        out[((size_t)b * D_MODEL + d0 + ty + i) * NPTS + n0 + tx] = tile[tx][ty + i];
}

// V slice of QKV [M,1152] (cols 768..1152) -> VT [B,H,64,NPTS]
__global__ __launch_bounds__(256) void k_vt(const unsigned short* __restrict__ qkv,
                                            unsigned short* __restrict__ vt) {
    __shared__ unsigned short tile[32][33];
    int b = blockIdx.z;
    int h = blockIdx.y >> 1, d0 = (blockIdx.y & 1) * 32;
    int n0 = blockIdx.x * 32;
    int tx = threadIdx.x, ty = threadIdx.y;
#pragma unroll
    for (int i = 0; i < 32; i += 8)
        tile[ty + i][tx] =
            qkv[((size_t)b * NPTS + n0 + ty + i) * 1152 + 768 + h * 64 + d0 + tx];
    __syncthreads();
#pragma unroll
    for (int i = 0; i < 32; i += 8)
        vt[(((size_t)(b * NHEAD + h) * 64) + d0 + ty + i) * NPTS + n0 + tx] = tile[tx][ty + i];
}

// LayerNorm over D=384 (bf16 in/out, fp32 g/b), one block (128 thr) per row
__global__ __launch_bounds__(128) void k_layernorm(const unsigned short* __restrict__ x,
                                                   const float* __restrict__ g,
                                                   const float* __restrict__ bt,
                                                   unsigned short* __restrict__ y) {
    int row = blockIdx.x, t = threadIdx.x;
    const unsigned short* xr = x + (size_t)row * D_MODEL;
    float v0 = bf2f(xr[t]), v1 = bf2f(xr[t + 128]), v2 = bf2f(xr[t + 256]);
    float s = v0 + v1 + v2;
    float s2 = v0 * v0 + v1 * v1 + v2 * v2;
#pragma unroll
    for (int off = 32; off > 0; off >>= 1) {
        s += __shfl_xor(s, off, 64);
        s2 += __shfl_xor(s2, off, 64);
    }
    __shared__ float ps[2], ps2[2];
    if ((t & 63) == 0) { ps[t >> 6] = s; ps2[t >> 6] = s2; }
    __syncthreads();
    s = ps[0] + ps[1];
    s2 = ps2[0] + ps2[1];
    float mean = s * (1.0f / 384.0f);
    float var = s2 * (1.0f / 384.0f) - mean * mean;
    var = fmaxf(var, 0.0f);
    float inv = 1.0f / sqrtf(var + 1e-5f);
    unsigned short* yr = y + (size_t)row * D_MODEL;
    yr[t]       = f2bf((v0 - mean) * inv * g[t]       + bt[t]);
    yr[t + 128] = f2bf((v1 - mean) * inv * g[t + 128] + bt[t + 128]);
    yr[t + 256] = f2bf((v2 - mean) * inv * g[t + 256] + bt[t + 256]);
}

// KNN v3: one wave per query, exact two-pass u32 selection.
__global__ __launch_bounds__(256) void k_knn(const float* __restrict__ coords,
                                             int* __restrict__ idx) {
    __shared__ float4 cpts[NPTS];
    int b = blockIdx.x >> 9;             // 512 blocks per batch
    int q0 = (blockIdx.x & 511) * 4;     // 4 queries (waves) per block
    const float* cb = coords + (size_t)b * 3 * NPTS;
    int tid = threadIdx.x;
#pragma unroll
    for (int i = 0; i < 8; i++) {
        int m = tid + i * 256;
        float x = cb[m], y = cb[NPTS + m], z = cb[2 * NPTS + m];
        float sq = __fadd_rn(__fadd_rn(__fmul_rn(x, x), __fmul_rn(y, y)), __fmul_rn(z, z));
        cpts[m] = make_float4(x, y, z, sq);
    }
    __syncthreads();
    int wv = tid >> 6, lane = tid & 63;
    int n = q0 + wv;
    float4 qp = cpts[n];
    float qx = qp.x, qy = qp.y, qz = qp.z, sqn = qp.w;
    unsigned keys[32];
    unsigned h[8];
#pragma unroll
    for (int k = 0; k < 8; k++) h[k] = 0xFFFFFFFFu;
#pragma unroll
    for (int j = 0; j < 32; j++) {
        float4 cp = cpts[j * 64 + lane];
        float dot = __fadd_rn(__fadd_rn(__fmul_rn(qx, cp.x), __fmul_rn(qy, cp.y)),
                              __fmul_rn(qz, cp.z));
        float d2 = __fsub_rn(__fadd_rn(sqn, cp.w), __fmul_rn(2.0f, dot));
        unsigned u = __float_as_uint(d2);
        u ^= (unsigned)(((int)u >> 31)) | 0x80000000u;  // order-preserving map
        keys[j] = u;
        unsigned cur = u;  // unconditional sorted-insert (no-op if u >= h[7])
#pragma unroll
        for (int t2 = 0; t2 < 8; t2++) {
            unsigned lo = h[t2] < cur ? h[t2] : cur;
            cur = h[t2] < cur ? cur : h[t2];
            h[t2] = lo;
        }
    }
    // Merge: serial-extract 8 smallest values of the union -> T8
    unsigned curh = h[0];
    unsigned T8 = 0;
#pragma unroll
    for (int r = 0; r < 8; r++) {
        unsigned w = curh;
#pragma unroll
        for (int off = 1; off < 64; off <<= 1) {
            unsigned o = __shfl_xor(w, off, 64);
            w = o < w ? o : w;
        }
        T8 = w;
        if (r < 7) {
            unsigned long long mask = __ballot(curh == w);
            if (curh == w && (mask & ((1ull << lane) - 1ull)) == 0) {
#pragma unroll
                for (int t2 = 0; t2 < 7; t2++) h[t2] = h[t2 + 1];
                h[7] = 0xFFFFFFFFu;
                curh = h[0];
            }
        }
    }
    // Pass 2: emit strict winners; track min eq index
    int* outr = idx + ((size_t)b * NPTS + n) * 8;
    int cnt = 0;
    unsigned meq = 0xFFFFFFFFu;
#pragma unroll
    for (int j = 0; j < 32; j++) {
        unsigned m = (unsigned)(j * 64 + lane);
        bool strict = keys[j] < T8;
        unsigned long long msk = __ballot(strict);
        if (strict) {
            int pos = cnt + (int)__popcll(msk & ((1ull << lane) - 1ull));
            outr[pos] = (int)m;
        }
        cnt += (int)__popcll(msk);
        if (keys[j] == T8 && m < meq) meq = m;
    }
    // Fill remaining slots with lowest-index key==T8 candidates
    while (cnt < 8) {
        unsigned w = meq;
#pragma unroll
        for (int off = 1; off < 64; off <<= 1) {
            unsigned o = __shfl_xor(w, off, 64);
            w = o < w ? o : w;
        }
        bool winner = (meq == w);
        if (winner) outr[cnt] = (int)w;
        cnt++;
        if (cnt >= 8) break;
        if (winner) {  // rare: advance to next eq index > w
            meq = 0xFFFFFFFFu;
#pragma unroll
            for (int j = 0; j < 32; j++) {
                unsigned m = (unsigned)(j * 64 + lane);
                if (keys[j] == T8 && m > w && m < meq) meq = m;
            }
        }
    }
}

// MFMA GEMM v6: 128x128 tile, BK=64, global_load_lds staging, C^T-layout MFMA.
// 1D grid with XCD-aware decode: each XCD owns 16 contiguous row-panels (y),
// so the A-panel working set per XCD (~1.5-3 MB) fits its private 4 MB L2
// instead of being refetched by all 8 XCDs. NY=128 for all our shapes.
// A bf16 [M,K] (lda), WT bf16 [N,K], bias fp32, res/C bf16 (ldc).
__global__ __launch_bounds__(256) void k_gemm(const unsigned short* __restrict__ A, int lda,
                                              const unsigned short* __restrict__ WT,
                                              const float* __restrict__ bias,
                                              const unsigned short* __restrict__ res,
                                              unsigned short* __restrict__ C, int ldc,
                                              int K, int act, int NX) {
    __shared__ unsigned short Alds[2 * 128 * 32];  // 16 KB: [kc][row][32]
    __shared__ unsigned short Wlds[2 * 128 * 32];  // 16 KB: [kc][nrow][32]
    int tid = threadIdx.x;
    int wv = tid >> 6, lane = tid & 63;
    int l15 = lane & 15, quad = lane >> 4;
    // XCD-aware block decode: id%8 = XCD (HW round-robin). 16 y-panels per XCD.
    int id = blockIdx.x;
    int xcd = id & 7, slot = id >> 3;
    int y = xcd * 16 + slot / NX;
    int x = slot % NX;
    int row0 = y * 128, col0 = x * 128;
    int wm = wv >> 1, wn = wv & 1;
    int wbase = tid & 192;  // wv*64
    floatx4 acc[4][4];
#pragma unroll
    for (int i = 0; i < 4; i++)
#pragma unroll
        for (int j = 0; j < 4; j++) acc[i][j] = (floatx4){0.f, 0.f, 0.f, 0.f};
    for (int k0 = 0; k0 < K; k0 += 64) {
#pragma unroll
        for (int i = 0; i < 4; i++) {
            int idx = i * 256 + tid;
            int kc = idx >> 9, row = (idx >> 2) & 127, ko = idx & 3;
            unsigned short* ldst = Alds + (size_t)(i * 256 + wbase) * 8;  // idx*16B, wave-uniform
            gload_lds16(A + (size_t)(row0 + row) * lda + k0 + kc * 32 + ko * 8, ldst);
            unsigned short* ldstw = Wlds + (size_t)(i * 256 + wbase) * 8;
            gload_lds16(WT + (size_t)(col0 + row) * K + k0 + kc * 32 + ko * 8, ldstw);
        }
        __syncthreads();  // drains global_load_lds
#pragma unroll
        for (int kc = 0; kc < 2; kc++) {
            short8 af[4], bf[4];
#pragma unroll
            for (int i = 0; i < 4; i++)
                af[i] = *(const short8*)&Alds[kc * 4096 + (wm * 64 + i * 16 + l15) * 32 + quad * 8];
#pragma unroll
            for (int j = 0; j < 4; j++)
                bf[j] = *(const short8*)&Wlds[kc * 4096 + (wn * 64 + j * 16 + l15) * 32 + quad * 8];
#pragma unroll
            for (int i = 0; i < 4; i++)
#pragma unroll
                for (int j = 0; j < 4; j++)
                    acc[i][j] =
                        __builtin_amdgcn_mfma_f32_16x16x32_bf16(bf[j], af[i], acc[i][j], 0, 0, 0);
        }
        __syncthreads();
    }
    // acc[i][j] is C^T-layout: D rows = n (quad*4+reg within j-tile), cols = m (l15)
#pragma unroll
    for (int i = 0; i < 4; i++) {
        int r = row0 + wm * 64 + i * 16 + l15;
#pragma unroll
        for (int j = 0; j < 4; j++) {
            int cb = col0 + wn * 64 + j * 16 + quad * 4;
            float4 bv = bias ? *(const float4*)(bias + cb) : make_float4(0.f, 0.f, 0.f, 0.f);
            float v0 = acc[i][j][0] + bv.x;
            float v1 = acc[i][j][1] + bv.y;
            float v2 = acc[i][j][2] + bv.z;
            float v3 = acc[i][j][3] + bv.w;
            if (act == 1) {
                v0 = gelu_tanh(v0); v1 = gelu_tanh(v1);
                v2 = gelu_tanh(v2); v3 = gelu_tanh(v3);
            }
            if (res) {
                uint2 rv = *(const uint2*)(res + (size_t)r * ldc + cb);
                const unsigned short* rs = (const unsigned short*)&rv;
                v0 += bf2f(rs[0]); v1 += bf2f(rs[1]);
                v2 += bf2f(rs[2]); v3 += bf2f(rs[3]);
            }
            ushort4 u;
            u.x = f2bf(v0); u.y = f2bf(v1); u.z = f2bf(v2); u.w = f2bf(v3);
            *(ushort4*)(C + (size_t)r * ldc + cb) = u;
        }
    }
}

// MFMA flash attention v7 = v6 + XCD-aware block decode: each XCD owns 6 whole
// (b,h) pairs (16 q-tiles each), so its K/V stream (6 x 512 KB = 3 MB) fits the
// private 4 MB L2 -> the per-tile vmcnt(0) barrier drain becomes an L2 hit and
// cross-XCD K/V refetch (was ~4x over-fetch, FETCH_SIZE 104 MB) disappears.
__global__ __launch_bounds__(256, 3) void k_attn(const unsigned short* __restrict__ qkv,
                                                 const unsigned short* __restrict__ vt,
                                                 unsigned short* __restrict__ attn) {
    __shared__ unsigned short Klds[2][64 * 64];  // 16 KB: [buf][key][dim] (swizzled slots)
    __shared__ unsigned short VTl[2][64 * 64];   // 16 KB: [buf][dim][key] (swizzled slots)
    // XCD decode: id%8 = XCD; 96 slots/XCD = 6 pairs x 16 tiles
    int id = blockIdx.x;
    int xcd = id & 7, slot = id >> 3;
    int pair = xcd * 6 + (slot >> 4);    // 48 pairs total, 6 per XCD
    int tile = slot & 15;
    int b = pair / 6, h = pair % 6;
    int tid = threadIdx.x;
    int wv = tid >> 6, lane = tid & 63;
    int l15 = lane & 15, quad = lane >> 4;
    int qbase = tile * 128 + wv * 32;
    const unsigned short* qkvb = qkv + (size_t)b * NPTS * 1152;
    const unsigned short* vtb = vt + (size_t)(b * NHEAD + h) * 64 * NPTS;
    const float SC = 0.18033688011112042f;  // 0.125 * log2(e)
    short8 qf[2][2];
#pragma unroll
    for (int qt = 0; qt < 2; qt++) {
        const unsigned short* qptr =
            qkvb + (size_t)(qbase + qt * 16 + l15) * 1152 + h * 64 + quad * 8;
        qf[qt][0] = *(const short8*)qptr;
        qf[qt][1] = *(const short8*)(qptr + 32);
#pragma unroll
        for (int g = 0; g < 2; g++) {  // fold softmax scale into Q once
            short8 v = qf[qt][g];
#pragma unroll
            for (int e = 0; e < 8; e++)
                v[e] = (short)f2bf(bf2f((unsigned short)v[e]) * SC);
            qf[qt][g] = v;
        }
    }
    short4v ones4;
#pragma unroll
    for (int e = 0; e < 4; e++) ones4[e] = (short)0x3F80;  // bf16 1.0
    int x7 = l15 & 7;
    int sk0 = ((quad ^ x7) << 4);        // K read: swizzled slot, dims 0..31
    int sk1 = (((quad + 4) ^ x7) << 4);  // K read: swizzled slot, dims 32..63
    int vslot[4];                        // V read: per-kt swizzled slot
#pragma unroll
    for (int kt = 0; kt < 4; kt++) vslot[kt] = (((kt * 2 + (quad >> 1)) ^ x7) << 4);
    int vsub = (quad & 1) * 8;           // 8B half within the 16B slot
    int sdg = tid & 7;                   // staging: 16B slot within row
    floatx4 o[2][4];
#pragma unroll
    for (int qt = 0; qt < 2; qt++)
#pragma unroll
        for (int ct = 0; ct < 4; ct++) o[qt][ct] = (floatx4){0.f, 0.f, 0.f, 0.f};
    floatx4 l4[2];
    l4[0] = (floatx4){0.f, 0.f, 0.f, 0.f};
    l4[1] = (floatx4){0.f, 0.f, 0.f, 0.f};

    auto stage = [&](int c, int k0) {
#pragma unroll
        for (int i = 0; i < 2; i++) {
            int sid = i * 256 + tid;
            int row = sid >> 3;
            int sl = sdg ^ (row & 7);  // inverse-swizzled global slot
            gload_lds16(qkvb + (size_t)(k0 + row) * 1152 + 384 + h * 64 + sl * 8,
                        &Klds[c][(size_t)(i * 256 + (tid & 192)) * 8]);
            gload_lds16(vtb + (size_t)row * NPTS + k0 + sl * 8,
                        &VTl[c][(size_t)(i * 256 + (tid & 192)) * 8]);
        }
    };

    stage(0, 0);
    __syncthreads();
    for (int t = 0; t < 32; ++t) {
        int c = t & 1;
        if (t < 31) stage(c ^ 1, (t + 1) * 64);  // async DMA under compute
        const char* Kb = (const char*)&Klds[c][0];
        const char* Vb = (const char*)&VTl[c][0];
        short8 kf[4][2];
#pragma unroll
        for (int ct = 0; ct < 4; ct++) {
            kf[ct][0] = *(const short8*)(Kb + (ct * 16 + l15) * 128 + sk0);
            kf[ct][1] = *(const short8*)(Kb + (ct * 16 + l15) * 128 + sk1);
        }
        // QK^T swapped: lane holds P[key = ct*16 + quad*4 + r][q = l15]
        short4v pf16[2][4];
#pragma unroll
        for (int qt = 0; qt < 2; qt++) {
#pragma unroll
            for (int ct = 0; ct < 4; ct++) {
                floatx4 z = (floatx4){0.f, 0.f, 0.f, 0.f};
                z = __builtin_amdgcn_mfma_f32_16x16x32_bf16(kf[ct][0], qf[qt][0], z, 0, 0, 0);
                z = __builtin_amdgcn_mfma_f32_16x16x32_bf16(kf[ct][1], qf[qt][1], z, 0, 0, 0);
                float p0 = __builtin_amdgcn_exp2f(z[0]);
                float p1 = __builtin_amdgcn_exp2f(z[1]);
                float p2 = __builtin_amdgcn_exp2f(z[2]);
                float p3 = __builtin_amdgcn_exp2f(z[3]);
                u32x2 pk;
                pk.x = cvtpk(p0, p1);
                pk.y = cvtpk(p2, p3);
                pf16[qt][ct] = __builtin_bit_cast(short4v, pk);  // B-frag of mfma16
            }
        }
        // PV: o[dim-tile ctd] += V^T-frag(ctd,kt) x P-frag(kt), K=16 per step
        const char* vb0 = Vb + l15 * 128 + vsub;
#pragma unroll
        for (int ctd = 0; ctd < 4; ctd++) {
            short4v va[4];
#pragma unroll
            for (int kt = 0; kt < 4; kt++)
                va[kt] = *(const short4v*)(vb0 + ctd * 2048 + vslot[kt]);
#pragma unroll
            for (int kt = 0; kt < 4; kt++) {
#pragma unroll
                for (int qt = 0; qt < 2; qt++)
                    o[qt][ctd] = mfma16(va[kt], pf16[qt][kt], o[qt][ctd]);
            }
        }
#pragma unroll
        for (int qt = 0; qt < 2; qt++)
#pragma unroll
            for (int kt = 0; kt < 4; kt++) l4[qt] = mfma16(ones4, pf16[qt][kt], l4[qt]);
        if (t < 31) __syncthreads();  // next tile's DMA + this tile's readers done
    }
#pragma unroll
    for (int qt = 0; qt < 2; qt++) {
        float linv = 1.0f / l4[qt][0];
#pragma unroll
        for (int ct = 0; ct < 4; ct++) {
            ushort4 u;
            u.x = f2bf(o[qt][ct][0] * linv);
            u.y = f2bf(o[qt][ct][1] * linv);
            u.z = f2bf(o[qt][ct][2] * linv);
            u.w = f2bf(o[qt][ct][3] * linv);
            *(ushort4*)(attn + ((size_t)b * NPTS + qbase + qt * 16 + l15) * 384 + h * 64 +
                        ct * 16 + quad * 4) = u;
        }
    }
}

// Graph attention: gq/nk/nv are column-slices of GAP [M,1152]. One wave per point.
// Writes geom into CAT[:, 384:768] (row stride 768).
__global__ __launch_bounds__(64) void k_geom(const unsigned short* __restrict__ gap,
                                             const int* __restrict__ idx,
                                             unsigned short* __restrict__ cat) {
    int r = blockIdx.x;
    int b = r >> 11;
    int t = threadIdx.x;
    int nb[8];
#pragma unroll
    for (int k = 0; k < 8; k++) nb[k] = idx[(size_t)r * 8 + k];
    const unsigned short* gqr = gap + (size_t)r * 1152;
    float qv[6];
#pragma unroll
    for (int j = 0; j < 6; j++) qv[j] = bf2f(gqr[t + 64 * j]);
    float s[8];
#pragma unroll
    for (int k = 0; k < 8; k++) {
        const unsigned short* nkr = gap + ((size_t)b * NPTS + nb[k]) * 1152 + 384;
        float acc = 0.0f;
#pragma unroll
        for (int j = 0; j < 6; j++) acc += qv[j] * bf2f(nkr[t + 64 * j]);
#pragma unroll
        for (int mm = 32; mm > 0; mm >>= 1) acc += __shfl_xor(acc, mm, 64);
        s[k] = acc * 0.05103103630798287f;  // 1/sqrt(384)
    }
    float mx = s[0];
#pragma unroll
    for (int k = 1; k < 8; k++) mx = fmaxf(mx, s[k]);
    float w[8];
    float sum = 0.0f;
#pragma unroll
    for (int k = 0; k < 8; k++) { w[k] = __expf(s[k] - mx); sum += w[k]; }
    float inv = 1.0f / sum;
    unsigned short* outr = cat + (size_t)r * 768 + 384;
#pragma unroll
    for (int j = 0; j < 6; j++) {
        int d = t + 64 * j;
        float acc = 0.0f;
#pragma unroll
        for (int k = 0; k < 8; k++)
            acc += w[k] * bf2f(gap[((size_t)b * NPTS + nb[k]) * 1152 + 768 + d]);
        outr[d] = f2bf(acc * inv);
    }
}

extern "C" void kernel_launch(void* const* d_in, const int* in_sizes, int n_in,
                              void* d_out, int out_size, void* d_ws, size_t ws_size,
                              hipStream_t stream) {
    (void)in_sizes; (void)n_in; (void)out_size; (void)ws_size;
    const float* coords     = (const float*)d_in[0];
    const float* features   = (const float*)d_in[1];
    const float* ln1_g      = (const float*)d_in[2];
    const float* ln1_b      = (const float*)d_in[3];
    const float* w_qkv      = (const float*)d_in[4];
    const float* w_attn_out = (const float*)d_in[5];
    const float* b_attn_out = (const float*)d_in[6];
    const float* ga_wq      = (const float*)d_in[7];
    const float* ga_wk      = (const float*)d_in[8];
    const float* ga_wv      = (const float*)d_in[9];
    const float* merge_w    = (const float*)d_in[10];
    const float* merge_b    = (const float*)d_in[11];
    const float* ln2_g      = (const float*)d_in[12];
    const float* ln2_b      = (const float*)d_in[13];
    const float* ff_w1      = (const float*)d_in[14];
    const float* ff_b1      = (const float*)d_in[15];
    const float* ff_w2      = (const float*)d_in[16];
    const float* ff_b2      = (const float*)d_in[17];

    // Workspace (bf16 units of SZ = 6,291,456 elems = 12 MiB). Overlay schedule:
    //   u0 F | u1 NF->HB | u2-4 QKV -> (CAT=u2-3, GAP=u4-6 after attn/AO) |
    //   u5 ATTN | u6 VT (dead before GAP gemm) | F2=u4 after geom | T1=u5-6 |
    //   FFIN=u2 | IDX + transposed weights after u7 (~4.3 MB). Peak ~100 MiB.
    unsigned short* W0 = (unsigned short*)d_ws;
    const size_t SZ = (size_t)BATCH * NPTS * D_MODEL;  // 6291456
    unsigned short* F    = W0 + 0 * SZ;
    unsigned short* NF   = W0 + 1 * SZ;
    unsigned short* QKV  = W0 + 2 * SZ;   // 3 units
    unsigned short* ATTN = W0 + 5 * SZ;
    unsigned short* VT   = W0 + 6 * SZ;   // [B,H,64,NPTS] = 1 unit
    unsigned short* CAT  = W0 + 2 * SZ;   // 2 units [M,768]
    unsigned short* GAP  = W0 + 4 * SZ;   // 3 units [M,1152]
    unsigned short* F2   = W0 + 4 * SZ;   // after GAP dead
    unsigned short* HB   = W0 + 1 * SZ;
    unsigned short* T1   = W0 + 5 * SZ;   // 2 units [M,768]
    unsigned short* FFIN = W0 + 2 * SZ;
    int*            IDX  = (int*)(W0 + 7 * SZ);
    unsigned short* WTS  = W0 + 7 * SZ + 262144;  // after IDX (512 KB)
    unsigned short* qkvT = WTS;                     // [1152,384]
    unsigned short* aoT  = qkvT + 442368;           // [384,384]
    unsigned short* gaT  = aoT + 147456;            // [1152,384]
    unsigned short* mT   = gaT + 442368;            // [384,768]
    unsigned short* f1T  = mT + 294912;             // [768,384]
    unsigned short* f2T  = f1T + 294912;            // [384,768]

    const int M = BATCH * NPTS;  // 16384

    k_wprep<<<1872, dim3(32, 8), 0, stream>>>(w_qkv, w_attn_out, ga_wq, ga_wk, ga_wv,
                                              merge_w, ff_w1, ff_w2,
                                              qkvT, aoT, gaT, mT, f1T, f2T);
    k_transpose_in<<<dim3(NPTS / 32, D_MODEL / 32, BATCH), dim3(32, 8), 0, stream>>>(features, F);
    k_layernorm<<<M, 128, 0, stream>>>(F, ln1_g, ln1_b, NF);
    k_knn<<<BATCH * (NPTS / 4), 256, 0, stream>>>(coords, IDX);
    // QKV = NF @ w_qkv
    k_gemm<<<9 * 128, 256, 0, stream>>>(NF, 384, qkvT, nullptr, nullptr,
                                        QKV, 1152, 384, 0, 9);
    k_vt<<<dim3(NPTS / 32, 2 * NHEAD, BATCH), dim3(32, 8), 0, stream>>>(QKV, VT);
    k_attn<<<768, 256, 0, stream>>>(QKV, VT, ATTN);
    // CAT[:, :384] = ATTN @ w_attn_out + b_attn_out
    k_gemm<<<3 * 128, 256, 0, stream>>>(ATTN, 384, aoT, b_attn_out, nullptr,
                                        CAT, 768, 384, 0, 3);
    // GAP = NF @ [ga_wq | ga_wk | ga_wv]
    k_gemm<<<9 * 128, 256, 0, stream>>>(NF, 384, gaT, nullptr, nullptr,
                                        GAP, 1152, 384, 0, 9);
    k_geom<<<M, 64, 0, stream>>>(GAP, IDX, CAT);
    // F2 = CAT @ merge_w + merge_b + F
    k_gemm<<<3 * 128, 256, 0, stream>>>(CAT, 768, mT, merge_b, F,
                                        F2, 384, 768, 0, 3);
    k_layernorm<<<M, 128, 0, stream>>>(F2, ln2_g, ln2_b, HB);
    // T1 = gelu(HB @ ff_w1 + ff_b1)
    k_gemm<<<6 * 128, 256, 0, stream>>>(HB, 384, f1T, ff_b1, nullptr,
                                        T1, 768, 384, 1, 6);
    // FFIN = F2 + T1 @ ff_w2 + ff_b2
    k_gemm<<<3 * 128, 256, 0, stream>>>(T1, 768, f2T, ff_b2, F2,
                                        FFIN, 384, 768, 0, 3);
    k_transpose_out<<<dim3(D_MODEL / 32, NPTS / 32, BATCH), dim3(32, 8), 0, stream>>>(
        FFIN, (float*)d_out);
}